// Round 4
// baseline (12345.609 us; speedup 1.0000x reference)
//
#include <hip/hip_runtime.h>
#include <stdint.h>

#define DEV __device__ __forceinline__

// ---------------------------------------------------------------------------
// theta = conv1x1(x, w_theta) + b_theta, fp32 channels-last, zero-padded:
// layout [b][134][136][16]; real data at y=i+3, x=j+3 for i,j in [0,128)
// ---------------------------------------------------------------------------
__global__ void k_theta_f32(const float* __restrict__ x, const float* __restrict__ wt,
                            const float* __restrict__ bt, float* __restrict__ th)
{
  int idx = blockIdx.x*256 + threadIdx.x;
  const int TOT = 2*134*136;
  if (idx >= TOT) return;
  int xc = idx % 136; int t = idx / 136; int y = t % 134; int b = t / 134;
  int i = y - 3, j = xc - 3;
  float acc[16];
#pragma unroll
  for (int ic=0; ic<16; ++ic) acc[ic] = 0.f;
  if (i>=0 && i<128 && j>=0 && j<128) {
#pragma unroll
    for (int ic=0; ic<16; ++ic) acc[ic] = bt[ic];
    const float* xp = x + (size_t)b*64*16384 + i*128 + j;
    for (int cc=0; cc<64; ++cc) {
      float xv = xp[(size_t)cc*16384];
#pragma unroll
      for (int ic=0; ic<16; ++ic) acc[ic] += xv * wt[ic*64+cc];
    }
  }
  float* dst = th + (size_t)idx*16;
#pragma unroll
  for (int ic=0;ic<16;++ic) dst[ic] = acc[ic];
}

// ---------------------------------------------------------------------------
// phi_s and g_s, both fp32 channels-last zero-padded [b][HP][WX][16],
// via sxs stride-s VALID conv + bias. Real data at y=i+3,x=j+3, i,j in [0,HP-6)
// ---------------------------------------------------------------------------
template<int S, int HP, int WX>
__global__ void k_conv_f32(const float* __restrict__ x, const float* __restrict__ wp,
                           const float* __restrict__ bp, const float* __restrict__ wg,
                           const float* __restrict__ bg,
                           float* __restrict__ phi, float* __restrict__ gt)
{
  const int HSx = HP - 6;
  int idx = blockIdx.x*256 + threadIdx.x;
  const int TOT = 2*HP*WX;
  if (idx >= TOT) return;
  int xc = idx % WX; int t = idx / WX; int y = t % HP; int b = t / HP;
  int i = y-3, j = xc-3;
  float ph[16], gg[16];
#pragma unroll
  for (int ic=0;ic<16;++ic){ ph[ic]=0.f; gg[ic]=0.f; }
  if (i>=0 && i<HSx && j>=0 && j<HSx) {
#pragma unroll
    for (int ic=0;ic<16;++ic){ ph[ic]=bp[ic]; gg[ic]=bg[ic]; }
    for (int cc=0; cc<64; ++cc) {
      float xv[S*S];
#pragma unroll
      for (int a=0;a<S;++a)
#pragma unroll
        for (int bb=0;bb<S;++bb)
          xv[a*S+bb] = x[(((size_t)b*64+cc)*128 + i*S+a)*128 + j*S+bb];
#pragma unroll
      for (int ic=0;ic<16;++ic) {
        float accp=0.f, accg=0.f;
#pragma unroll
        for (int k=0;k<S*S;++k) {
          accp += xv[k]*wp[(ic*64+cc)*S*S + k];
          accg += xv[k]*wg[(ic*64+cc)*S*S + k];
        }
        ph[ic]+=accp; gg[ic]+=accg;
      }
    }
  }
  float* dp = phi + (size_t)idx*16;
  float* dg = gt  + (size_t)idx*16;
#pragma unroll
  for (int ic=0;ic<16;++ic){ dp[ic]=ph[ic]; dg[ic]=gg[ic]; }
}

// ---------------------------------------------------------------------------
// Brute-force flash attention, all fp32, no MFMA. One block (256 thr) per
// query (q = qi*32+qj, stride-4 grid, 1024 queries/batch). Query theta patch
// rows are 4*qi+dr-1 (unfold pad (1,2)). Keys processed in chunks of 256.
// Online softmax (block-tree max/sum in LDS); PV: threads 0..195 own 4
// consecutive features each (f = p*16+c ordering, internally consistent).
// ---------------------------------------------------------------------------
template<int HS, int LG, int HP, int WX, int NCH>
__global__ void k_battn(const float* __restrict__ th, const float* __restrict__ phi,
                        const float* __restrict__ gf, float* __restrict__ yvf)
{
  __shared__ __align__(16) float thq[784];
  __shared__ float red[256];
  __shared__ float Pch[256];

  int t = threadIdx.x;
  int q = blockIdx.x;
  int b = blockIdx.y;
  int qi = q >> 5, qj = q & 31;

  // load theta patch for this query into LDS: theta rows 4*qi+dr-1 ->
  // padded-3 layout rows 4*qi+dr+2
  const float* thb = th + (((size_t)b*134 + 4*qi+2)*136 + 4*qj+2)*16;
  for (int s_=t; s_<784; s_+=256) {
    int p = s_ >> 4, c = s_ & 15;
    thq[s_] = thb[((p/7)*136 + (p%7))*16 + c];
  }
  __syncthreads();

  const float* phB = phi + (size_t)b*HP*WX*16;
  const float* gB  = gf  + (size_t)b*HP*WX*16;

  float m = -1.0e30f, l = 0.f;
  float y0=0.f, y1=0.f, y2=0.f, y3=0.f;
  int p_ = t >> 2, cb = (t & 3) * 4;
  const float* gbase = gB + ((p_/7)*WX + (p_%7))*16 + cb;   // valid only t<196

  for (int ch = 0; ch < NCH; ++ch) {
    // ---- score for key k = ch*256 + t ----
    int k = ch*256 + t;
    int kr = k >> LG, kc = k & (HS-1);
    const float* pb = phB + ((size_t)kr*WX + kc)*16;
    float s = 0.f;
#pragma unroll 7
    for (int p=0; p<49; ++p) {
      const float4* pp = (const float4*)(pb + ((p/7)*WX + (p%7))*16);
      const float4* tq = (const float4*)(thq + p*16);
      float4 A0=pp[0], A1=pp[1], A2=pp[2], A3=pp[3];
      float4 T0=tq[0], T1=tq[1], T2=tq[2], T3=tq[3];
      s += A0.x*T0.x + A0.y*T0.y + A0.z*T0.z + A0.w*T0.w
         + A1.x*T1.x + A1.y*T1.y + A1.z*T1.z + A1.w*T1.w
         + A2.x*T2.x + A2.y*T2.y + A2.z*T2.z + A2.w*T2.w
         + A3.x*T3.x + A3.y*T3.y + A3.z*T3.z + A3.w*T3.w;
    }
    s *= 10.0f;   // TEMP
    // ---- block max ----
    red[t] = s; __syncthreads();
#pragma unroll
    for (int off=128; off; off>>=1) { if (t<off) red[t] = fmaxf(red[t], red[t+off]); __syncthreads(); }
    float mnew = fmaxf(m, red[0]);
    float al = __expf(m - mnew);
    float pv = __expf(s - mnew);
    __syncthreads();                       // everyone has read red[0]
    // ---- block sum ----
    red[t] = pv; Pch[t] = pv; __syncthreads();
#pragma unroll
    for (int off=128; off; off>>=1) { if (t<off) red[t] += red[t+off]; __syncthreads(); }
    l = l*al + red[0];
    // ---- PV ----
    if (t < 196) {
      y0 *= al; y1 *= al; y2 *= al; y3 *= al;
#pragma unroll 8
      for (int kk=0; kk<256; ++kk) {
        int k2 = ch*256 + kk;
        int kr2 = k2 >> LG, kc2 = k2 & (HS-1);
        float pw = Pch[kk];
        float4 v = *(const float4*)(gbase + ((size_t)kr2*WX + kc2)*16);
        y0 += pw*v.x; y1 += pw*v.y; y2 += pw*v.z; y3 += pw*v.w;
      }
    }
    m = mnew;
    __syncthreads();                       // protect red/Pch for next chunk
  }
  if (t < 196) {
    float inv = 1.0f / l;
    float4 o; o.x = y0*inv; o.y = y1*inv; o.z = y2*inv; o.w = y3*inv;
    *(float4*)(yvf + ((size_t)b*1024 + q)*784 + t*4) = o;
  }
}

// ---------------------------------------------------------------------------
// fold (stride-4, pad 3) + /mask -> y_cl[b][i][j][48].
// Pixel (i,j) gathers queries (qi,qj) with 4*qi+dr-3 == i, 4*qj+dc-3 == j.
// mask = cnti * cntj (separable coverage count).
// ---------------------------------------------------------------------------
template<int SC>
__global__ void k_fold_f32(const float* __restrict__ yvf, float* __restrict__ ycl)
{
  int idx = blockIdx.x*256 + threadIdx.x;
  if (idx >= 2*128*128) return;
  int j = idx & 127; int t = idx >> 7; int i = t & 127; int b = t >> 7;
  float a[16];
#pragma unroll
  for (int c=0;c<16;++c) a[c]=0.f;
  const float* yb = yvf + (size_t)b*1024*784;

  int drs[2], qis[2], cnti=0;
  int dcs[2], qjs[2], cntj=0;
#pragma unroll
  for (int dr=0; dr<7; ++dr) {
    int tr = i + 3 - dr;
    if (tr >= 0 && (tr & 3) == 0 && (tr >> 2) < 32) { drs[cnti]=dr; qis[cnti]=tr>>2; ++cnti; }
  }
#pragma unroll
  for (int dc=0; dc<7; ++dc) {
    int tc = j + 3 - dc;
    if (tc >= 0 && (tc & 3) == 0 && (tc >> 2) < 32) { dcs[cntj]=dc; qjs[cntj]=tc>>2; ++cntj; }
  }
  for (int u=0; u<cnti; ++u) {
    for (int v=0; v<cntj; ++v) {
      const float* src = yb + (size_t)(qis[u]*32 + qjs[v])*784 + (drs[u]*7 + dcs[v])*16;
      float4 v0 = *(const float4*)(src);
      float4 v1 = *(const float4*)(src+4);
      float4 v2 = *(const float4*)(src+8);
      float4 v3 = *(const float4*)(src+12);
      a[0]+=v0.x; a[1]+=v0.y; a[2]+=v0.z; a[3]+=v0.w;
      a[4]+=v1.x; a[5]+=v1.y; a[6]+=v1.z; a[7]+=v1.w;
      a[8]+=v2.x; a[9]+=v2.y; a[10]+=v2.z; a[11]+=v2.w;
      a[12]+=v3.x; a[13]+=v3.y; a[14]+=v3.z; a[15]+=v3.w;
    }
  }
  float inv = 1.0f / (float)(cnti*cntj);
  float* dst = ycl + (size_t)idx*48 + SC*16;
#pragma unroll
  for (int c=0;c<16;++c) dst[c] = a[c]*inv;
}

// ---------------------------------------------------------------------------
// out = conv1x1(y, w_out) + b_out + x
// ---------------------------------------------------------------------------
__global__ void k_final(const float* __restrict__ ycl, const float* __restrict__ wo,
                        const float* __restrict__ bo, const float* __restrict__ x,
                        float* __restrict__ out)
{
  __shared__ float wl[64*48];
  for (int t = threadIdx.x; t < 64*48; t += 256) wl[t] = wo[t];
  __syncthreads();
  int idx = blockIdx.x*256 + threadIdx.x;
  if (idx >= 2*128*128) return;
  int j = idx & 127; int t = idx >> 7; int i = t & 127; int b = t >> 7;
  float y[48];
  const float* ys = ycl + (size_t)idx*48;
#pragma unroll
  for (int c=0;c<48;++c) y[c] = ys[c];
  const float* xb = x + (size_t)b*64*16384 + i*128 + j;
  float* ob = out + (size_t)b*64*16384 + i*128 + j;
  for (int o=0;o<64;++o) {
    float s = bo[o];
#pragma unroll
    for (int c=0;c<48;++c) s += y[c]*wl[o*48+c];
    ob[(size_t)o*16384] = s + xb[(size_t)o*16384];
  }
}

// ---------------------------------------------------------------------------
extern "C" void kernel_launch(void* const* d_in, const int* in_sizes, int n_in,
                              void* d_out, int out_size, void* d_ws, size_t ws_size,
                              hipStream_t stream)
{
  const float* x  = (const float*)d_in[0];
  const float* wt = (const float*)d_in[1];
  const float* bt = (const float*)d_in[2];
  const float* wp0= (const float*)d_in[3];
  const float* bp0= (const float*)d_in[4];
  const float* wg0= (const float*)d_in[5];
  const float* bg0= (const float*)d_in[6];
  const float* wp1= (const float*)d_in[7];
  const float* bp1= (const float*)d_in[8];
  const float* wg1= (const float*)d_in[9];
  const float* bg1= (const float*)d_in[10];
  const float* wp2= (const float*)d_in[11];
  const float* bp2= (const float*)d_in[12];
  const float* wg2= (const float*)d_in[13];
  const float* bg2= (const float*)d_in[14];
  const float* wo = (const float*)d_in[15];
  const float* bo = (const float*)d_in[16];
  float* out = (float*)d_out;

  char* ws = (char*)d_ws;
  size_t off = 0;
  auto alloc = [&](size_t bytes)->char* { char* p = ws + off; off += (bytes + 255) & ~(size_t)255; return p; };
  float* thf  = (float*)alloc(2ull*134*136*16*4);
  float* phf0 = (float*)alloc(2ull*134*136*16*4);
  float* phf1 = (float*)alloc(2ull*70*72*16*4);
  float* phf2 = (float*)alloc(2ull*38*40*16*4);
  float* gf0  = (float*)alloc(2ull*134*136*16*4);
  float* gf1  = (float*)alloc(2ull*70*72*16*4);
  float* gf2  = (float*)alloc(2ull*38*40*16*4);
  float* yvf  = (float*)alloc(2ull*1024*784*4);
  float* ycl  = (float*)alloc(2ull*128*128*48*4);
  (void)ws_size; (void)in_sizes; (void)n_in; (void)out_size;

  k_theta_f32<<<(2*134*136+255)/256, 256, 0, stream>>>(x, wt, bt, thf);
  k_conv_f32<1,134,136><<<(2*134*136+255)/256,256,0,stream>>>(x, wp0,bp0,wg0,bg0, phf0, gf0);
  k_conv_f32<2,70,72>  <<<(2*70*72 +255)/256,256,0,stream>>>(x, wp1,bp1,wg1,bg1, phf1, gf1);
  k_conv_f32<4,38,40>  <<<(2*38*40 +255)/256,256,0,stream>>>(x, wp2,bp2,wg2,bg2, phf2, gf2);

  dim3 ag(1024, 2);
  k_battn<128,7,134,136,64><<<ag,256,0,stream>>>(thf, phf0, gf0, yvf);
  k_fold_f32<0><<<128,256,0,stream>>>(yvf, ycl);
  k_battn<64,6,70,72,16><<<ag,256,0,stream>>>(thf, phf1, gf1, yvf);
  k_fold_f32<1><<<128,256,0,stream>>>(yvf, ycl);
  k_battn<32,5,38,40,4><<<ag,256,0,stream>>>(thf, phf2, gf2, yvf);
  k_fold_f32<2><<<128,256,0,stream>>>(yvf, ycl);
  k_final<<<128,256,0,stream>>>(ycl, wo, bo, x, out);
}

// Round 5
// 2139.235 us; speedup vs baseline: 5.7710x; 5.7710x over previous
//
#include <hip/hip_runtime.h>
#include <stdint.h>

typedef __attribute__((ext_vector_type(8))) short bf16x8;
typedef __attribute__((ext_vector_type(4))) float f32x4;

#define DEV __device__ __forceinline__

DEV float bf2f(unsigned short u){ union{unsigned int i; float f;} v; v.i=((unsigned int)u)<<16; return v.f; }
DEV unsigned short f2bf(float f){ union{float f; unsigned int i;} v; v.f=f; unsigned int x=v.i;
  return (unsigned short)((x + 0x7fffu + ((x>>16)&1u)) >> 16); }

// ---------------------------------------------------------------------------
// theta = (conv1x1(x, w_theta) + b_theta) * 10*log2(e), channels-last bf16,
// zero-padded: layout [b][134][136][16]; real pixel (i,j) at row i+3, col j+3
// ---------------------------------------------------------------------------
__global__ void k_theta(const float* __restrict__ x, const float* __restrict__ wt,
                        const float* __restrict__ bt, unsigned short* __restrict__ th)
{
  int idx = blockIdx.x*256 + threadIdx.x;
  const int TOT = 2*134*136;
  if (idx >= TOT) return;
  int xc = idx % 136; int t = idx / 136; int y = t % 134; int b = t / 134;
  int i = y - 3, j = xc - 3;
  float acc[16];
#pragma unroll
  for (int ic=0; ic<16; ++ic) acc[ic] = 0.f;
  if (i>=0 && i<128 && j>=0 && j<128) {
#pragma unroll
    for (int ic=0; ic<16; ++ic) acc[ic] = bt[ic];
    const float* xp = x + (size_t)b*64*16384 + i*128 + j;
    for (int cc=0; cc<64; ++cc) {
      float xv = xp[(size_t)cc*16384];
#pragma unroll
      for (int ic=0; ic<16; ++ic) acc[ic] += xv * wt[ic*64+cc];
    }
    const float TEMPC = 14.426950408889634f; // 10 * log2(e)
#pragma unroll
    for (int ic=0; ic<16; ++ic) acc[ic] *= TEMPC;
  }
  unsigned short o[16];
#pragma unroll
  for (int ic=0;ic<16;++ic) o[ic]=f2bf(acc[ic]);
  uint4* dst = (uint4*)(th + (size_t)idx*16);
  dst[0]=*(uint4*)&o[0]; dst[1]=*(uint4*)&o[8];
}

// ---------------------------------------------------------------------------
// phi_s (channels-last bf16 padded [b][HP][WX][16]) and g_s (channels-first
// f32 padded [b][16][HP][WX]) via sxs stride-s VALID conv + bias.
// ---------------------------------------------------------------------------
template<int S, int HP, int WX>
__global__ void k_conv(const float* __restrict__ x, const float* __restrict__ wp,
                       const float* __restrict__ bp, const float* __restrict__ wg,
                       const float* __restrict__ bg,
                       unsigned short* __restrict__ phi, float* __restrict__ gt)
{
  const int HSx = HP - 6;
  int idx = blockIdx.x*256 + threadIdx.x;
  const int TOT = 2*HP*WX;
  if (idx >= TOT) return;
  int xc = idx % WX; int t = idx / WX; int y = t % HP; int b = t / HP;
  int i = y-3, j = xc-3;
  float ph[16], gg[16];
#pragma unroll
  for (int ic=0;ic<16;++ic){ ph[ic]=0.f; gg[ic]=0.f; }
  if (i>=0 && i<HSx && j>=0 && j<HSx) {
#pragma unroll
    for (int ic=0;ic<16;++ic){ ph[ic]=bp[ic]; gg[ic]=bg[ic]; }
    for (int cc=0; cc<64; ++cc) {
      float xv[S*S];
#pragma unroll
      for (int a=0;a<S;++a)
#pragma unroll
        for (int bb=0;bb<S;++bb)
          xv[a*S+bb] = x[(((size_t)b*64+cc)*128 + i*S+a)*128 + j*S+bb];
#pragma unroll
      for (int ic=0;ic<16;++ic) {
        float accp=0.f, accg=0.f;
#pragma unroll
        for (int k=0;k<S*S;++k) {
          accp += xv[k]*wp[(ic*64+cc)*S*S + k];
          accg += xv[k]*wg[(ic*64+cc)*S*S + k];
        }
        ph[ic]+=accp; gg[ic]+=accg;
      }
    }
  }
  unsigned short o[16];
#pragma unroll
  for (int ic=0;ic<16;++ic) o[ic]=f2bf(ph[ic]);
  uint4* dst = (uint4*)(phi + (size_t)idx*16);
  dst[0]=*(uint4*)&o[0]; dst[1]=*(uint4*)&o[8];
#pragma unroll
  for (int ic=0;ic<16;++ic)
    gt[(((size_t)b*16+ic)*HP + y)*WX + xc] = gg[ic];
}

// ---------------------------------------------------------------------------
// g8[b][sh][c][y][x] = g_pad[b][c][y][x+sh]  (bf16, 8 shifted copies so the
// PV B-fragment = one aligned 16B load of 8 consecutive keys)
// ---------------------------------------------------------------------------
template<int HP, int WX>
__global__ void k_shift(const float* __restrict__ gt, unsigned short* __restrict__ g8)
{
  const int WX8 = WX/8;
  int idx = blockIdx.x*256 + threadIdx.x;
  const int TOT = 2*8*16*HP*WX8;
  if (idx >= TOT) return;
  int x8 = idx % WX8; int t = idx/WX8; int y = t % HP; t/=HP;
  int c = t%16; t/=16; int sh = t%8; int b = t/8;
  const float* src = gt + (((size_t)b*16+c)*HP + y)*WX;
  unsigned short o[8];
#pragma unroll
  for (int jj=0;jj<8;++jj) {
    int xx = x8*8 + sh + jj;
    float v = (xx < WX) ? src[xx] : 0.f;
    o[jj]=f2bf(v);
  }
  *(uint4*)(g8 + ((((size_t)b*8+sh)*16+c)*HP + y)*(size_t)WX + x8*8) = *(uint4*)&o[0];
}

// ---------------------------------------------------------------------------
// Stats pass, key-chunk-parallel: wave-private flash stats for 16 queries
// over keys [chunk*CK, chunk*CK+CK). No LDS, no barriers. Writes partial
// (m, l) in exp2 domain to mP/lP[(chunk*2+b)*1024 + q].
// Queries: stride-4 grid, 1024/batch; query (qi,qj) theta-patch base at
// padded row 4*qi+2, col 4*qj+2; adjacent query = +4 pixels (128 B).
// ---------------------------------------------------------------------------
template<int HS, int LG, int HP, int WX, int CK>
__global__ void k_stats(const unsigned short* __restrict__ th,
                        const unsigned short* __restrict__ phi,
                        float* __restrict__ mP, float* __restrict__ lP)
{
  int tid = threadIdx.x;
  int w = tid >> 6, lane = tid & 63, l15 = lane & 15, g = lane >> 4;
  int b = blockIdx.y;
  int chunk = blockIdx.z;
  int q16 = blockIdx.x*4 + w;           // [0,64): which 16-query group
  int qi = q16 >> 1, qj0 = (q16 & 1) * 16;
  const char* thB  = (const char*)th  + (size_t)b*134*136*32;
  const char* phiB = (const char*)phi + (size_t)b*HP*WX*32;
  int tb = ((4*qi+2)*136 + 4*(qj0 + l15) + 2)*32 + ((g&1)<<4);
  const bf16x8 ZV = {0,0,0,0,0,0,0,0};
  float m[4], l[4];
#pragma unroll
  for (int r=0;r<4;++r){ m[r] = -3.0e38f; l[r] = 0.f; }
#pragma unroll 1
  for (int kk0 = chunk*CK; kk0 < chunk*CK + CK; kk0 += 32) {
    asm volatile("" : "+v"(tb));
    int kr = kk0 >> LG, kc = kk0 & (HS-1);
    int base0 = (kr*WX + kc + l15)*32 + ((g&1)<<4);
    int base1 = base0 + 512;
    f32x4 s0{0.f,0.f,0.f,0.f}, s1{0.f,0.f,0.f,0.f};
#pragma unroll
    for (int ks=0; ks<25; ++ks) {
      int p0 = 2*ks;
      int p1 = (2*ks+1 > 48) ? 48 : 2*ks+1;
      int KA0 = ((p0/7)*136 + (p0%7))*32;
      int KA1 = ((p1/7)*136 + (p1%7))*32;
      int KB0 = ((p0/7)*WX  + (p0%7))*32;
      int KB1 = ((p1/7)*WX  + (p1%7))*32;
      int selA = (g & 2) ? KA1 : KA0;
      int selB = (g & 2) ? KB1 : KB0;
      bf16x8 a0 = *(const bf16x8*)(thB + tb + selA);
      if (ks == 24) { bool z = (g & 2) != 0; a0 = z ? ZV : a0; }
      bf16x8 b0 = *(const bf16x8*)(phiB + base0 + selB);
      bf16x8 b1 = *(const bf16x8*)(phiB + base1 + selB);
      s0 = __builtin_amdgcn_mfma_f32_16x16x32_bf16(a0, b0, s0, 0,0,0);
      s1 = __builtin_amdgcn_mfma_f32_16x16x32_bf16(a0, b1, s1, 0,0,0);
    }
    float tm[4];
#pragma unroll
    for (int r=0;r<4;++r) tm[r] = fmaxf(s0[r], s1[r]);
#pragma unroll
    for (int st=1; st<16; st<<=1)
#pragma unroll
      for (int r=0;r<4;++r) tm[r] = fmaxf(tm[r], __shfl_xor(tm[r], st));
    float mn[4], ss[4];
#pragma unroll
    for (int r=0;r<4;++r) {
      mn[r] = fmaxf(m[r], tm[r]);
      ss[r] = __builtin_amdgcn_exp2f(s0[r]-mn[r]) + __builtin_amdgcn_exp2f(s1[r]-mn[r]);
    }
#pragma unroll
    for (int st=1; st<16; st<<=1)
#pragma unroll
      for (int r=0;r<4;++r) ss[r] += __shfl_xor(ss[r], st);
#pragma unroll
    for (int r=0;r<4;++r) {
      l[r] = l[r]*__builtin_amdgcn_exp2f(m[r]-mn[r]) + ss[r];
      m[r] = mn[r];
    }
  }
  if (l15 == 0) {
#pragma unroll
    for (int r=0;r<4;++r) {
      size_t o = (size_t)(chunk*2 + b)*1024 + q16*16 + g*4 + r;
      mP[o] = m[r];
      lP[o] = l[r];
    }
  }
}

// ---------------------------------------------------------------------------
// Merge per-chunk stats: mG = max, lG = sum l_c * 2^(m_c - mG)
// ---------------------------------------------------------------------------
__global__ void k_comb1(const float* __restrict__ mP, const float* __restrict__ lP,
                        float* __restrict__ mG, float* __restrict__ lG, int nch)
{
  int idx = blockIdx.x*256 + threadIdx.x;
  if (idx >= 2048) return;
  float m = -3.0e38f;
  for (int c=0;c<nch;++c) m = fmaxf(m, mP[c*2048 + idx]);
  float l = 0.f;
  for (int c=0;c<nch;++c) l += lP[c*2048 + idx] * exp2f(mP[c*2048 + idx] - m);
  mG[idx] = m; lG[idx] = l;
}

// ---------------------------------------------------------------------------
// PV pass, key-chunk-parallel. Q-tile 64 (4 row-tiles of 16 stride-4 queries),
// 8 waves, 256 keys/iter. QK replayed (bit-identical to k_stats); P =
// exp2(sc - mG) <= 1 written to linear P-LDS; waves 0-6 accumulate PV for
// e-chunks p=7w..7w+6 from shifted g8; partial acc (fp32, no divide) to
// accP[(chunk*2+b)*1024*784 + q*784 + p*16 + c].
// ---------------------------------------------------------------------------
template<int HS, int LG, int HP, int WX, int CK>
__global__ void __launch_bounds__(512, 2)
k_pv(const unsigned short* __restrict__ th, const unsigned short* __restrict__ phi,
     const unsigned short* __restrict__ g8, const float* __restrict__ mG,
     float* __restrict__ accP)
{
  __shared__ __align__(16) char smem[32768];   // P: 64 q x 256 k bf16

  int tid = threadIdx.x;
  int w = tid >> 6, lane = tid & 63, l15 = lane & 15, g = lane >> 4;
  int b = blockIdx.y;
  int chunk = blockIdx.z;
  int q0 = blockIdx.x * 64;          // within batch, [0,1024)
  int qi0 = q0 >> 5;                 // even

  float m_r[4][4];
#pragma unroll
  for (int rt=0;rt<4;++rt)
#pragma unroll
    for (int r=0;r<4;++r)
      m_r[rt][r] = mG[(size_t)b*1024 + q0 + rt*16 + g*4 + r];

  f32x4 acc[4][7];
#pragma unroll
  for (int rt=0;rt<4;++rt)
#pragma unroll
    for (int et=0;et<7;++et) acc[rt][et] = f32x4{0.f,0.f,0.f,0.f};

  const char* thB  = (const char*)th  + (size_t)b*134*136*32;
  const char* phiB = (const char*)phi + (size_t)b*HP*WX*32;
  const char* g8B  = (const char*)g8  + (size_t)b*8*16*HP*WX*2;
  const int CPLANE = HP*WX*2, EPLANE = 16*HP*WX*2, WXB = WX*2;
  int laneV = l15*CPLANE + g*16 + w*WXB;
  // A-base: row-tile offsets {same row qj+0..15, qj+16..31, next qi row x2}
  int tb = ((4*qi0+2)*136 + 4*l15 + 2)*32 + ((g&1)<<4);
  const int OFFRT[4] = {0, 64*32, 4*136*32, 4*136*32 + 64*32};
  const bf16x8 ZV = {0,0,0,0,0,0,0,0};
  const int ITERS = CK/256;

#pragma unroll 1
  for (int it = 0; it < ITERS; ++it) {
    int k0 = chunk*CK + it*256;
    asm volatile("" : "+v"(tb));
    // ---------------- QK ----------------
    f32x4 sc[4][2];
#pragma unroll
    for (int rt=0;rt<4;++rt){ sc[rt][0]=f32x4{0.f,0.f,0.f,0.f}; sc[rt][1]=f32x4{0.f,0.f,0.f,0.f}; }
    int kr_w = (k0 + w*32) >> LG;
    int kc_w = (w*32) & (HS-1);
    int base0 = (kr_w*WX + kc_w + l15)*32 + ((g&1)<<4);
    int base1 = base0 + 512;
#pragma unroll
    for (int ks=0; ks<25; ++ks) {
      int p0 = 2*ks;
      int p1 = (2*ks+1 > 48) ? 48 : 2*ks+1;
      int KA0 = ((p0/7)*136 + (p0%7))*32;
      int KA1 = ((p1/7)*136 + (p1%7))*32;
      int KB0 = ((p0/7)*WX  + (p0%7))*32;
      int KB1 = ((p1/7)*WX  + (p1%7))*32;
      int selA = (g & 2) ? KA1 : KA0;
      int selB = (g & 2) ? KB1 : KB0;
      bf16x8 a0 = *(const bf16x8*)(thB + tb + selA + OFFRT[0]);
      bf16x8 a1 = *(const bf16x8*)(thB + tb + selA + OFFRT[1]);
      bf16x8 a2 = *(const bf16x8*)(thB + tb + selA + OFFRT[2]);
      bf16x8 a3 = *(const bf16x8*)(thB + tb + selA + OFFRT[3]);
      if (ks == 24) {
        bool z = (g & 2) != 0;
        a0 = z ? ZV : a0; a1 = z ? ZV : a1; a2 = z ? ZV : a2; a3 = z ? ZV : a3;
      }
      bf16x8 b0 = *(const bf16x8*)(phiB + base0 + selB);
      bf16x8 b1 = *(const bf16x8*)(phiB + base1 + selB);
      sc[0][0] = __builtin_amdgcn_mfma_f32_16x16x32_bf16(a0, b0, sc[0][0], 0,0,0);
      sc[0][1] = __builtin_amdgcn_mfma_f32_16x16x32_bf16(a0, b1, sc[0][1], 0,0,0);
      sc[1][0] = __builtin_amdgcn_mfma_f32_16x16x32_bf16(a1, b0, sc[1][0], 0,0,0);
      sc[1][1] = __builtin_amdgcn_mfma_f32_16x16x32_bf16(a1, b1, sc[1][1], 0,0,0);
      sc[2][0] = __builtin_amdgcn_mfma_f32_16x16x32_bf16(a2, b0, sc[2][0], 0,0,0);
      sc[2][1] = __builtin_amdgcn_mfma_f32_16x16x32_bf16(a2, b1, sc[2][1], 0,0,0);
      sc[3][0] = __builtin_amdgcn_mfma_f32_16x16x32_bf16(a3, b0, sc[3][0], 0,0,0);
      sc[3][1] = __builtin_amdgcn_mfma_f32_16x16x32_bf16(a3, b1, sc[3][1], 0,0,0);
    }
    // ---------------- P = exp2(S - m_global), write linear P_lds ----------------
#pragma unroll
    for (int rt=0;rt<4;++rt) {
#pragma unroll
      for (int r=0;r<4;++r) {
        float pa = __builtin_amdgcn_exp2f(sc[rt][0][r] - m_r[rt][r]);
        float pb = __builtin_amdgcn_exp2f(sc[rt][1][r] - m_r[rt][r]);
        int q_ = rt*16 + g*4 + r;
        *(unsigned short*)(smem + q_*512 + (w*32 + l15)*2)      = f2bf(pa);
        *(unsigned short*)(smem + q_*512 + (w*32 + 16 + l15)*2) = f2bf(pb);
      }
    }
    __syncthreads();                               // P ready
    // ---------------- PV ----------------
    if (w < 7) {
#pragma unroll
      for (int ks2=0; ks2<8; ++ks2) {
        int kk = k0 + ks2*32;
        int krv = kk >> LG;
        int kcb = kk & (HS-1);
        bf16x8 pf[4];
#pragma unroll
        for (int rt=0;rt<4;++rt) {
          int off = (rt*16 + l15)*512 + ks2*64 + g*16;
          pf[rt] = *(const bf16x8*)(smem + off);
        }
        int vb = krv*WXB + kcb*2 + laneV;
        bf16x8 vf[7];
#pragma unroll
        for (int et=0;et<7;++et)
          vf[et] = *(const bf16x8*)(g8B + vb + et*EPLANE);
#pragma unroll
        for (int rt=0;rt<4;++rt)
#pragma unroll
          for (int et=0;et<7;++et)
            acc[rt][et] = __builtin_amdgcn_mfma_f32_16x16x32_bf16(pf[rt], vf[et], acc[rt][et], 0,0,0);
      }
    }
    __syncthreads();                               // protect P for next iter
  }
  if (w < 7) {
    float* accB = accP + ((size_t)(chunk*2 + b)*1024)*784;
#pragma unroll
    for (int rt=0;rt<4;++rt)
#pragma unroll
      for (int et=0;et<7;++et)
#pragma unroll
        for (int r=0;r<4;++r)
          accB[(size_t)(q0 + rt*16 + g*4 + r)*784 + (w*7+et)*16 + l15] = acc[rt][et][r];
  }
}

// ---------------------------------------------------------------------------
// Sum partial accs over chunks, divide by l -> yvf[b*1024+q][784] fp32
// ---------------------------------------------------------------------------
__global__ void k_comb2(const float* __restrict__ accP, const float* __restrict__ lG,
                        float* __restrict__ yvf, int nch)
{
  int idx = blockIdx.x*256 + threadIdx.x;
  if (idx >= 2048*196) return;
  int bq = idx / 196, f4 = idx % 196;
  float4 s = {0.f,0.f,0.f,0.f};
  for (int c=0;c<nch;++c) {
    float4 v = *(const float4*)(accP + ((size_t)(c*2048 + bq))*784 + f4*4);
    s.x += v.x; s.y += v.y; s.z += v.z; s.w += v.w;
  }
  float inv = 1.0f / lG[bq];
  s.x*=inv; s.y*=inv; s.z*=inv; s.w*=inv;
  *(float4*)(yvf + (size_t)bq*784 + f4*4) = s;
}

// ---------------------------------------------------------------------------
// fold (stride-4, pad 3) + /mask -> y_cl[b][i][j][48]
// ---------------------------------------------------------------------------
template<int SC>
__global__ void k_fold_f32(const float* __restrict__ yvf, float* __restrict__ ycl)
{
  int idx = blockIdx.x*256 + threadIdx.x;
  if (idx >= 2*128*128) return;
  int j = idx & 127; int t = idx >> 7; int i = t & 127; int b = t >> 7;
  float a[16];
#pragma unroll
  for (int c=0;c<16;++c) a[c]=0.f;
  const float* yb = yvf + (size_t)b*1024*784;

  int drs[2], qis[2], cnti=0;
  int dcs[2], qjs[2], cntj=0;
#pragma unroll
  for (int dr=0; dr<7; ++dr) {
    int tr = i + 3 - dr;
    if (tr >= 0 && (tr & 3) == 0 && (tr >> 2) < 32) { drs[cnti]=dr; qis[cnti]=tr>>2; ++cnti; }
  }
#pragma unroll
  for (int dc=0; dc<7; ++dc) {
    int tc = j + 3 - dc;
    if (tc >= 0 && (tc & 3) == 0 && (tc >> 2) < 32) { dcs[cntj]=dc; qjs[cntj]=tc>>2; ++cntj; }
  }
  for (int u=0; u<cnti; ++u) {
    for (int v=0; v<cntj; ++v) {
      const float* src = yb + (size_t)(qis[u]*32 + qjs[v])*784 + (drs[u]*7 + dcs[v])*16;
      float4 v0 = *(const float4*)(src);
      float4 v1 = *(const float4*)(src+4);
      float4 v2 = *(const float4*)(src+8);
      float4 v3 = *(const float4*)(src+12);
      a[0]+=v0.x; a[1]+=v0.y; a[2]+=v0.z; a[3]+=v0.w;
      a[4]+=v1.x; a[5]+=v1.y; a[6]+=v1.z; a[7]+=v1.w;
      a[8]+=v2.x; a[9]+=v2.y; a[10]+=v2.z; a[11]+=v2.w;
      a[12]+=v3.x; a[13]+=v3.y; a[14]+=v3.z; a[15]+=v3.w;
    }
  }
  float inv = 1.0f / (float)(cnti*cntj);
  float* dst = ycl + (size_t)idx*48 + SC*16;
#pragma unroll
  for (int c=0;c<16;++c) dst[c] = a[c]*inv;
}

// ---------------------------------------------------------------------------
// out = conv1x1(y, w_out) + b_out + x
// ---------------------------------------------------------------------------
__global__ void k_final(const float* __restrict__ ycl, const float* __restrict__ wo,
                        const float* __restrict__ bo, const float* __restrict__ x,
                        float* __restrict__ out)
{
  __shared__ float wl[64*48];
  for (int t = threadIdx.x; t < 64*48; t += 256) wl[t] = wo[t];
  __syncthreads();
  int idx = blockIdx.x*256 + threadIdx.x;
  if (idx >= 2*128*128) return;
  int j = idx & 127; int t = idx >> 7; int i = t & 127; int b = t >> 7;
  float y[48];
  const float* ys = ycl + (size_t)idx*48;
#pragma unroll
  for (int c=0;c<48;++c) y[c] = ys[c];
  const float* xb = x + (size_t)b*64*16384 + i*128 + j;
  float* ob = out + (size_t)b*64*16384 + i*128 + j;
  for (int o=0;o<64;++o) {
    float s = bo[o];
#pragma unroll
    for (int c=0;c<48;++c) s += y[c]*wl[o*48+c];
    ob[(size_t)o*16384] = s + xb[(size_t)o*16384];
  }
}

// ---------------------------------------------------------------------------
extern "C" void kernel_launch(void* const* d_in, const int* in_sizes, int n_in,
                              void* d_out, int out_size, void* d_ws, size_t ws_size,
                              hipStream_t stream)
{
  const float* x  = (const float*)d_in[0];
  const float* wt = (const float*)d_in[1];
  const float* bt = (const float*)d_in[2];
  const float* wp0= (const float*)d_in[3];
  const float* bp0= (const float*)d_in[4];
  const float* wg0= (const float*)d_in[5];
  const float* bg0= (const float*)d_in[6];
  const float* wp1= (const float*)d_in[7];
  const float* bp1= (const float*)d_in[8];
  const float* wg1= (const float*)d_in[9];
  const float* bg1= (const float*)d_in[10];
  const float* wp2= (const float*)d_in[11];
  const float* bp2= (const float*)d_in[12];
  const float* wg2= (const float*)d_in[13];
  const float* bg2= (const float*)d_in[14];
  const float* wo = (const float*)d_in[15];
  const float* bo = (const float*)d_in[16];
  float* out = (float*)d_out;

  char* ws = (char*)d_ws;
  size_t off = 0;
  auto alloc = [&](size_t bytes)->char* { char* p = ws + off; off += (bytes + 255) & ~(size_t)255; return p; };
  unsigned short* th  = (unsigned short*)alloc(2ull*134*136*16*2);
  unsigned short* ph0 = (unsigned short*)alloc(2ull*134*136*16*2);
  unsigned short* ph1 = (unsigned short*)alloc(2ull*70*72*16*2);
  unsigned short* ph2 = (unsigned short*)alloc(2ull*38*40*16*2);
  float* gt0 = (float*)alloc(2ull*16*134*136*4);
  float* gt1 = (float*)alloc(2ull*16*70*72*4);
  float* gt2 = (float*)alloc(2ull*16*38*40*4);
  unsigned short* g80 = (unsigned short*)alloc(2ull*8*16*134*136*2);
  unsigned short* g81 = (unsigned short*)alloc(2ull*8*16*70*72*2);
  unsigned short* g82 = (unsigned short*)alloc(2ull*8*16*38*40*2);
  float* mP  = (float*)alloc(8ull*2048*4);
  float* lP  = (float*)alloc(8ull*2048*4);
  float* mG  = (float*)alloc(2048*4);
  float* lG  = (float*)alloc(2048*4);
  float* accP= (float*)alloc(8ull*2048*784*4);
  float* yvf = (float*)alloc(2048ull*784*4);
  float* ycl = (float*)alloc(2ull*128*128*48*4);
  (void)ws_size; (void)in_sizes; (void)n_in; (void)out_size;

  k_theta<<<(2*134*136+255)/256, 256, 0, stream>>>(x, wt, bt, th);
  k_conv<1,134,136><<<(2*134*136+255)/256,256,0,stream>>>(x, wp0,bp0,wg0,bg0, ph0, gt0);
  k_conv<2,70,72>  <<<(2*70*72 +255)/256,256,0,stream>>>(x, wp1,bp1,wg1,bg1, ph1, gt1);
  k_conv<4,38,40>  <<<(2*38*40 +255)/256,256,0,stream>>>(x, wp2,bp2,wg2,bg2, ph2, gt2);
  k_shift<134,136><<<(2*8*16*134*17+255)/256,256,0,stream>>>(gt0, g80);
  k_shift<70,72>  <<<(2*8*16*70*9 +255)/256,256,0,stream>>>(gt1, g81);
  k_shift<38,40>  <<<(2*8*16*38*5 +255)/256,256,0,stream>>>(gt2, g82);

  const int CB2 = (2048*196 + 255)/256;
  // ---- scale 0 (s=1): 16384 keys, 8 chunks of 2048 ----
  k_stats<128,7,134,136,2048><<<dim3(16,2,8),256,0,stream>>>(th, ph0, mP, lP);
  k_comb1<<<8,256,0,stream>>>(mP, lP, mG, lG, 8);
  k_pv<128,7,134,136,2048><<<dim3(16,2,8),512,0,stream>>>(th, ph0, g80, mG, accP);
  k_comb2<<<CB2,256,0,stream>>>(accP, lG, yvf, 8);
  k_fold_f32<0><<<128,256,0,stream>>>(yvf, ycl);
  // ---- scale 1 (s=2): 4096 keys, 2 chunks of 2048 ----
  k_stats<64,6,70,72,2048><<<dim3(16,2,2),256,0,stream>>>(th, ph1, mP, lP);
  k_comb1<<<8,256,0,stream>>>(mP, lP, mG, lG, 2);
  k_pv<64,6,70,72,2048><<<dim3(16,2,2),512,0,stream>>>(th, ph1, g81, mG, accP);
  k_comb2<<<CB2,256,0,stream>>>(accP, lG, yvf, 2);
  k_fold_f32<1><<<128,256,0,stream>>>(yvf, ycl);
  // ---- scale 2 (s=4): 1024 keys, 1 chunk ----
  k_stats<32,5,38,40,1024><<<dim3(16,2,1),256,0,stream>>>(th, ph2, mP, lP);
  k_comb1<<<8,256,0,stream>>>(mP, lP, mG, lG, 1);
  k_pv<32,5,38,40,1024><<<dim3(16,2,1),512,0,stream>>>(th, ph2, g82, mG, accP);
  k_comb2<<<CB2,256,0,stream>>>(accP, lG, yvf, 1);
  k_fold_f32<2><<<128,256,0,stream>>>(yvf, ycl);

  k_final<<<128,256,0,stream>>>(ycl, wo, bo, x, out);
}

// Round 6
// 1807.652 us; speedup vs baseline: 6.8296x; 1.1834x over previous
//
#include <hip/hip_runtime.h>
#include <stdint.h>

typedef __attribute__((ext_vector_type(8))) short bf16x8;
typedef __attribute__((ext_vector_type(4))) float f32x4;

#define DEV __device__ __forceinline__

DEV float bf2f(unsigned short u){ union{unsigned int i; float f;} v; v.i=((unsigned int)u)<<16; return v.f; }
DEV unsigned short f2bf(float f){ union{float f; unsigned int i;} v; v.f=f; unsigned int x=v.i;
  return (unsigned short)((x + 0x7fffu + ((x>>16)&1u)) >> 16); }

// ---------------------------------------------------------------------------
// Fused s=1 prep: theta = (W_t x + b_t)*10*log2(e)  [bf16 CL padded 134x136x16]
//                 phi0  = W_p x + b_p               [bf16 CL padded]
//                 g0    = W_g x + b_g               [f32 CF padded 16x134x136]
// 512 blocks x 256 thr = 64 pixels x 4 cc-groups; LDS reduction.
// Borders are pre-zeroed by hipMemsetAsync.
// ---------------------------------------------------------------------------
__global__ void k_prep1(const float* __restrict__ x,
                        const float* __restrict__ wt, const float* __restrict__ bt,
                        const float* __restrict__ wp, const float* __restrict__ bp,
                        const float* __restrict__ wg, const float* __restrict__ bg,
                        unsigned short* __restrict__ th, unsigned short* __restrict__ ph,
                        float* __restrict__ gt)
{
  __shared__ float red[3][64][48];
  int tid = threadIdx.x;
  int grp = tid >> 6, pixl = tid & 63;
  int pix = blockIdx.x*64 + pixl;          // [0, 32768)
  int b = pix >> 14, p = pix & 16383, i = p >> 7, j = p & 127;
  float a[48];
#pragma unroll
  for (int c=0;c<48;++c) a[c]=0.f;
  const float* xb = x + (size_t)b*64*16384 + p;
#pragma unroll
  for (int c4=0; c4<4; ++c4) {
    int cc = grp*16 + c4*4;
    float xv[4];
#pragma unroll
    for (int u=0;u<4;++u) xv[u] = xb[(size_t)(cc+u)*16384];
#pragma unroll
    for (int ic=0;ic<16;++ic) {
      float4 w0 = *(const float4*)(wt + ic*64 + cc);
      float4 w1 = *(const float4*)(wp + ic*64 + cc);
      float4 w2 = *(const float4*)(wg + ic*64 + cc);
      a[ic]    += xv[0]*w0.x + xv[1]*w0.y + xv[2]*w0.z + xv[3]*w0.w;
      a[16+ic] += xv[0]*w1.x + xv[1]*w1.y + xv[2]*w1.z + xv[3]*w1.w;
      a[32+ic] += xv[0]*w2.x + xv[1]*w2.y + xv[2]*w2.z + xv[3]*w2.w;
    }
  }
  if (grp) {
#pragma unroll
    for (int c=0;c<48;++c) red[grp-1][pixl][c] = a[c];
  }
  __syncthreads();
  if (grp == 0) {
#pragma unroll
    for (int c=0;c<48;++c) a[c] += red[0][pixl][c] + red[1][pixl][c] + red[2][pixl][c];
    const float TEMPC = 14.426950408889634f;
    unsigned short o[16];
#pragma unroll
    for (int ic=0;ic<16;++ic) o[ic] = f2bf((a[ic]+bt[ic])*TEMPC);
    uint4* d0 = (uint4*)(th + ((size_t)(b*134 + i+3)*136 + (j+3))*16);
    d0[0]=*(uint4*)&o[0]; d0[1]=*(uint4*)&o[8];
#pragma unroll
    for (int ic=0;ic<16;++ic) o[ic] = f2bf(a[16+ic]+bp[ic]);
    uint4* d1 = (uint4*)(ph + ((size_t)(b*134 + i+3)*136 + (j+3))*16);
    d1[0]=*(uint4*)&o[0]; d1[1]=*(uint4*)&o[8];
#pragma unroll
    for (int ic=0;ic<16;++ic)
      gt[(((size_t)b*16+ic)*134 + i+3)*136 + (j+3)] = a[32+ic]+bg[ic];
  }
}

// ---------------------------------------------------------------------------
// s=2 conv: phi1 (bf16 CL padded 70x72x16), g1 (f32 CF padded 16x70x72).
// 128 blocks x 256 thr = 64 pixels x 4 cc-groups.
// ---------------------------------------------------------------------------
__global__ void k_conv2(const float* __restrict__ x,
                        const float* __restrict__ wp, const float* __restrict__ bp,
                        const float* __restrict__ wg, const float* __restrict__ bg,
                        unsigned short* __restrict__ phi, float* __restrict__ gt)
{
  __shared__ float red[3][64][32];
  int tid = threadIdx.x;
  int grp = tid >> 6, pixl = tid & 63;
  int pix = blockIdx.x*64 + pixl;          // [0, 8192)
  int b = pix >> 12, p = pix & 4095, i = p >> 6, j = p & 63;
  float a[32];
#pragma unroll
  for (int c=0;c<32;++c) a[c]=0.f;
  const float* xb = x + (size_t)b*64*16384 + (i*2)*128 + j*2;
#pragma unroll
  for (int c0=0; c0<16; ++c0) {
    int cc = grp*16 + c0;
    const float* xp = xb + (size_t)cc*16384;
    float xv[4];
    xv[0]=xp[0]; xv[1]=xp[1]; xv[2]=xp[128]; xv[3]=xp[129];
#pragma unroll
    for (int ic=0;ic<16;++ic) {
      float4 w0 = *(const float4*)(wp + (ic*64+cc)*4);
      float4 w1 = *(const float4*)(wg + (ic*64+cc)*4);
      a[ic]    += xv[0]*w0.x + xv[1]*w0.y + xv[2]*w0.z + xv[3]*w0.w;
      a[16+ic] += xv[0]*w1.x + xv[1]*w1.y + xv[2]*w1.z + xv[3]*w1.w;
    }
  }
  if (grp) {
#pragma unroll
    for (int c=0;c<32;++c) red[grp-1][pixl][c] = a[c];
  }
  __syncthreads();
  if (grp == 0) {
#pragma unroll
    for (int c=0;c<32;++c) a[c] += red[0][pixl][c] + red[1][pixl][c] + red[2][pixl][c];
    unsigned short o[16];
#pragma unroll
    for (int ic=0;ic<16;++ic) o[ic] = f2bf(a[ic]+bp[ic]);
    uint4* d1 = (uint4*)(phi + ((size_t)(b*70 + i+3)*72 + (j+3))*16);
    d1[0]=*(uint4*)&o[0]; d1[1]=*(uint4*)&o[8];
#pragma unroll
    for (int ic=0;ic<16;++ic)
      gt[(((size_t)b*16+ic)*70 + i+3)*72 + (j+3)] = a[16+ic]+bg[ic];
  }
}

// ---------------------------------------------------------------------------
// Transpose s=4 weights: wT[k][32] with k = cc*16 + a*4 + bb; c<16 phi, else g
// ---------------------------------------------------------------------------
__global__ void k_wt4(const float* __restrict__ wp, const float* __restrict__ wg,
                      float* __restrict__ wT)
{
  int idx = blockIdx.x*256 + threadIdx.x;
  if (idx >= 1024*32) return;
  int k = idx >> 5, c = idx & 31;
  int cc = k >> 4, ksp = k & 15;
  float v = (c < 16) ? wp[(c*64+cc)*16 + ksp] : wg[((c-16)*64+cc)*16 + ksp];
  wT[idx] = v;
}

// ---------------------------------------------------------------------------
// s=4 conv: 256 blocks x 256 thr = 8 pixels x 32 out-channels (16 phi + 16 g).
// x patches (64cc x 4 x 4 = 1024 f32/pixel) staged in LDS; weights from wT
// (coalesced). phi2 bf16 CL padded 38x40x16; g2 f32 CF padded 16x38x40.
// ---------------------------------------------------------------------------
__global__ void k_conv4(const float* __restrict__ x, const float* __restrict__ wT,
                        const float* __restrict__ bp, const float* __restrict__ bg,
                        unsigned short* __restrict__ phi, float* __restrict__ gt)
{
  __shared__ float xs[8][1028];
  int tid = threadIdx.x;
  int pix0 = blockIdx.x*8;                 // [0,2048) step 8
  for (int idx = tid; idx < 8*1024; idx += 256) {
    int pl = idx >> 10, e = idx & 1023;
    int pix = pix0 + pl; int b = pix >> 10, p = pix & 1023, i = p >> 5, j = p & 31;
    int cc = e >> 4, a_ = (e >> 2) & 3, bb = e & 3;
    xs[pl][e] = x[(((size_t)b*64+cc)*128 + i*4+a_)*128 + j*4+bb];
  }
  __syncthreads();
  int pp = tid >> 5, icp = tid & 31;
  int pix = pix0 + pp; int b = pix >> 10, p = pix & 1023, i = p >> 5, j = p & 31;
  float acc = 0.f;
#pragma unroll 8
  for (int k4=0; k4<256; ++k4) {
    float4 xv = *(const float4*)(&xs[pp][k4*4]);
    acc += xv.x*wT[(k4*4  )*32+icp] + xv.y*wT[(k4*4+1)*32+icp]
         + xv.z*wT[(k4*4+2)*32+icp] + xv.w*wT[(k4*4+3)*32+icp];
  }
  int ic = icp & 15;
  if (icp < 16)
    phi[(((size_t)(b*38 + i+3)*40) + (j+3))*16 + ic] = f2bf(acc + bp[ic]);
  else
    gt[(((size_t)b*16+ic)*38 + i+3)*40 + (j+3)] = acc + bg[ic];
}

// ---------------------------------------------------------------------------
// g8[b][sh][c][y][x] = g_pad[b][c][y][x+sh]  (bf16, 8 shifted copies so the
// PV B-fragment = one aligned 16B load of 8 consecutive keys)
// ---------------------------------------------------------------------------
template<int HP, int WX>
__global__ void k_shift(const float* __restrict__ gt, unsigned short* __restrict__ g8)
{
  const int WX8 = WX/8;
  int idx = blockIdx.x*256 + threadIdx.x;
  const int TOT = 2*8*16*HP*WX8;
  if (idx >= TOT) return;
  int x8 = idx % WX8; int t = idx/WX8; int y = t % HP; t/=HP;
  int c = t%16; t/=16; int sh = t%8; int b = t/8;
  const float* src = gt + (((size_t)b*16+c)*HP + y)*WX;
  unsigned short o[8];
#pragma unroll
  for (int jj=0;jj<8;++jj) {
    int xx = x8*8 + sh + jj;
    float v = (xx < WX) ? src[xx] : 0.f;
    o[jj]=f2bf(v);
  }
  *(uint4*)(g8 + ((((size_t)b*8+sh)*16+c)*HP + y)*(size_t)WX + x8*8) = *(uint4*)&o[0];
}

// ---------------------------------------------------------------------------
// Stats pass, key-chunk-parallel: wave-private flash stats for 16 queries
// over keys [chunk*CK, chunk*CK+CK). No LDS, no barriers. Writes partial
// (m, l) in exp2 domain to mP/lP[(chunk*2+b)*1024 + q].
// ---------------------------------------------------------------------------
template<int HS, int LG, int HP, int WX, int CK>
__global__ void k_stats(const unsigned short* __restrict__ th,
                        const unsigned short* __restrict__ phi,
                        float* __restrict__ mP, float* __restrict__ lP)
{
  int tid = threadIdx.x;
  int w = tid >> 6, lane = tid & 63, l15 = lane & 15, g = lane >> 4;
  int b = blockIdx.y;
  int chunk = blockIdx.z;
  int q16 = blockIdx.x*4 + w;           // [0,64): which 16-query group
  int qi = q16 >> 1, qj0 = (q16 & 1) * 16;
  const char* thB  = (const char*)th  + (size_t)b*134*136*32;
  const char* phiB = (const char*)phi + (size_t)b*HP*WX*32;
  int tb = ((4*qi+2)*136 + 4*(qj0 + l15) + 2)*32 + ((g&1)<<4);
  const bf16x8 ZV = {0,0,0,0,0,0,0,0};
  float m[4], l[4];
#pragma unroll
  for (int r=0;r<4;++r){ m[r] = -3.0e38f; l[r] = 0.f; }
#pragma unroll 1
  for (int kk0 = chunk*CK; kk0 < chunk*CK + CK; kk0 += 32) {
    asm volatile("" : "+v"(tb));
    int kr = kk0 >> LG, kc = kk0 & (HS-1);
    int base0 = (kr*WX + kc + l15)*32 + ((g&1)<<4);
    int base1 = base0 + 512;
    f32x4 s0{0.f,0.f,0.f,0.f}, s1{0.f,0.f,0.f,0.f};
#pragma unroll
    for (int ks=0; ks<25; ++ks) {
      int p0 = 2*ks;
      int p1 = (2*ks+1 > 48) ? 48 : 2*ks+1;
      int KA0 = ((p0/7)*136 + (p0%7))*32;
      int KA1 = ((p1/7)*136 + (p1%7))*32;
      int KB0 = ((p0/7)*WX  + (p0%7))*32;
      int KB1 = ((p1/7)*WX  + (p1%7))*32;
      int selA = (g & 2) ? KA1 : KA0;
      int selB = (g & 2) ? KB1 : KB0;
      bf16x8 a0 = *(const bf16x8*)(thB + tb + selA);
      if (ks == 24) { bool z = (g & 2) != 0; a0 = z ? ZV : a0; }
      bf16x8 b0 = *(const bf16x8*)(phiB + base0 + selB);
      bf16x8 b1 = *(const bf16x8*)(phiB + base1 + selB);
      s0 = __builtin_amdgcn_mfma_f32_16x16x32_bf16(a0, b0, s0, 0,0,0);
      s1 = __builtin_amdgcn_mfma_f32_16x16x32_bf16(a0, b1, s1, 0,0,0);
    }
    float tm[4];
#pragma unroll
    for (int r=0;r<4;++r) tm[r] = fmaxf(s0[r], s1[r]);
#pragma unroll
    for (int st=1; st<16; st<<=1)
#pragma unroll
      for (int r=0;r<4;++r) tm[r] = fmaxf(tm[r], __shfl_xor(tm[r], st));
    float mn[4], ss[4];
#pragma unroll
    for (int r=0;r<4;++r) {
      mn[r] = fmaxf(m[r], tm[r]);
      ss[r] = __builtin_amdgcn_exp2f(s0[r]-mn[r]) + __builtin_amdgcn_exp2f(s1[r]-mn[r]);
    }
#pragma unroll
    for (int st=1; st<16; st<<=1)
#pragma unroll
      for (int r=0;r<4;++r) ss[r] += __shfl_xor(ss[r], st);
#pragma unroll
    for (int r=0;r<4;++r) {
      l[r] = l[r]*__builtin_amdgcn_exp2f(m[r]-mn[r]) + ss[r];
      m[r] = mn[r];
    }
  }
  if (l15 == 0) {
#pragma unroll
    for (int r=0;r<4;++r) {
      size_t o = (size_t)(chunk*2 + b)*1024 + q16*16 + g*4 + r;
      mP[o] = m[r];
      lP[o] = l[r];
    }
  }
}

// ---------------------------------------------------------------------------
// Merge per-chunk stats: mG = max, lG = sum l_c * 2^(m_c - mG)
// ---------------------------------------------------------------------------
__global__ void k_comb1(const float* __restrict__ mP, const float* __restrict__ lP,
                        float* __restrict__ mG, float* __restrict__ lG, int nch)
{
  int idx = blockIdx.x*256 + threadIdx.x;
  if (idx >= 2048) return;
  float m = -3.0e38f;
  for (int c=0;c<nch;++c) m = fmaxf(m, mP[c*2048 + idx]);
  float l = 0.f;
  for (int c=0;c<nch;++c) l += lP[c*2048 + idx] * exp2f(mP[c*2048 + idx] - m);
  mG[idx] = m; lG[idx] = l;
}

// ---------------------------------------------------------------------------
// PV pass, key-chunk-parallel. Q-tile 64, 8 waves, 256 keys/iter. QK replayed
// (bit-identical to k_stats); P = exp2(sc - mG) <= 1 to linear P-LDS; waves
// 0-6 accumulate PV for e-chunks p=7w..7w+6 from shifted g8; fp32 partials.
// ---------------------------------------------------------------------------
template<int HS, int LG, int HP, int WX, int CK>
__global__ void __launch_bounds__(512, 2)
k_pv(const unsigned short* __restrict__ th, const unsigned short* __restrict__ phi,
     const unsigned short* __restrict__ g8, const float* __restrict__ mG,
     float* __restrict__ accP)
{
  __shared__ __align__(16) char smem[32768];   // P: 64 q x 256 k bf16

  int tid = threadIdx.x;
  int w = tid >> 6, lane = tid & 63, l15 = lane & 15, g = lane >> 4;
  int b = blockIdx.y;
  int chunk = blockIdx.z;
  int q0 = blockIdx.x * 64;          // within batch, [0,1024)
  int qi0 = q0 >> 5;                 // even

  float m_r[4][4];
#pragma unroll
  for (int rt=0;rt<4;++rt)
#pragma unroll
    for (int r=0;r<4;++r)
      m_r[rt][r] = mG[(size_t)b*1024 + q0 + rt*16 + g*4 + r];

  f32x4 acc[4][7];
#pragma unroll
  for (int rt=0;rt<4;++rt)
#pragma unroll
    for (int et=0;et<7;++et) acc[rt][et] = f32x4{0.f,0.f,0.f,0.f};

  const char* thB  = (const char*)th  + (size_t)b*134*136*32;
  const char* phiB = (const char*)phi + (size_t)b*HP*WX*32;
  const char* g8B  = (const char*)g8  + (size_t)b*8*16*HP*WX*2;
  const int CPLANE = HP*WX*2, EPLANE = 16*HP*WX*2, WXB = WX*2;
  int laneV = l15*CPLANE + g*16 + w*WXB;
  int tb = ((4*qi0+2)*136 + 4*l15 + 2)*32 + ((g&1)<<4);
  const int OFFRT[4] = {0, 64*32, 4*136*32, 4*136*32 + 64*32};
  const bf16x8 ZV = {0,0,0,0,0,0,0,0};
  const int ITERS = CK/256;

#pragma unroll 1
  for (int it = 0; it < ITERS; ++it) {
    int k0 = chunk*CK + it*256;
    asm volatile("" : "+v"(tb));
    // ---------------- QK ----------------
    f32x4 sc[4][2];
#pragma unroll
    for (int rt=0;rt<4;++rt){ sc[rt][0]=f32x4{0.f,0.f,0.f,0.f}; sc[rt][1]=f32x4{0.f,0.f,0.f,0.f}; }
    int kr_w = (k0 + w*32) >> LG;
    int kc_w = (w*32) & (HS-1);
    int base0 = (kr_w*WX + kc_w + l15)*32 + ((g&1)<<4);
    int base1 = base0 + 512;
#pragma unroll
    for (int ks=0; ks<25; ++ks) {
      int p0 = 2*ks;
      int p1 = (2*ks+1 > 48) ? 48 : 2*ks+1;
      int KA0 = ((p0/7)*136 + (p0%7))*32;
      int KA1 = ((p1/7)*136 + (p1%7))*32;
      int KB0 = ((p0/7)*WX  + (p0%7))*32;
      int KB1 = ((p1/7)*WX  + (p1%7))*32;
      int selA = (g & 2) ? KA1 : KA0;
      int selB = (g & 2) ? KB1 : KB0;
      bf16x8 a0 = *(const bf16x8*)(thB + tb + selA + OFFRT[0]);
      bf16x8 a1 = *(const bf16x8*)(thB + tb + selA + OFFRT[1]);
      bf16x8 a2 = *(const bf16x8*)(thB + tb + selA + OFFRT[2]);
      bf16x8 a3 = *(const bf16x8*)(thB + tb + selA + OFFRT[3]);
      if (ks == 24) {
        bool z = (g & 2) != 0;
        a0 = z ? ZV : a0; a1 = z ? ZV : a1; a2 = z ? ZV : a2; a3 = z ? ZV : a3;
      }
      bf16x8 b0 = *(const bf16x8*)(phiB + base0 + selB);
      bf16x8 b1 = *(const bf16x8*)(phiB + base1 + selB);
      sc[0][0] = __builtin_amdgcn_mfma_f32_16x16x32_bf16(a0, b0, sc[0][0], 0,0,0);
      sc[0][1] = __builtin_amdgcn_mfma_f32_16x16x32_bf16(a0, b1, sc[0][1], 0,0,0);
      sc[1][0] = __builtin_amdgcn_mfma_f32_16x16x32_bf16(a1, b0, sc[1][0], 0,0,0);
      sc[1][1] = __builtin_amdgcn_mfma_f32_16x16x32_bf16(a1, b1, sc[1][1], 0,0,0);
      sc[2][0] = __builtin_amdgcn_mfma_f32_16x16x32_bf16(a2, b0, sc[2][0], 0,0,0);
      sc[2][1] = __builtin_amdgcn_mfma_f32_16x16x32_bf16(a2, b1, sc[2][1], 0,0,0);
      sc[3][0] = __builtin_amdgcn_mfma_f32_16x16x32_bf16(a3, b0, sc[3][0], 0,0,0);
      sc[3][1] = __builtin_amdgcn_mfma_f32_16x16x32_bf16(a3, b1, sc[3][1], 0,0,0);
    }
    // ---------------- P = exp2(S - m_global), write linear P_lds ----------------
#pragma unroll
    for (int rt=0;rt<4;++rt) {
#pragma unroll
      for (int r=0;r<4;++r) {
        float pa = __builtin_amdgcn_exp2f(sc[rt][0][r] - m_r[rt][r]);
        float pb = __builtin_amdgcn_exp2f(sc[rt][1][r] - m_r[rt][r]);
        int q_ = rt*16 + g*4 + r;
        *(unsigned short*)(smem + q_*512 + (w*32 + l15)*2)      = f2bf(pa);
        *(unsigned short*)(smem + q_*512 + (w*32 + 16 + l15)*2) = f2bf(pb);
      }
    }
    __syncthreads();                               // P ready
    // ---------------- PV ----------------
    if (w < 7) {
#pragma unroll
      for (int ks2=0; ks2<8; ++ks2) {
        int kk = k0 + ks2*32;
        int krv = kk >> LG;
        int kcb = kk & (HS-1);
        bf16x8 pf[4];
#pragma unroll
        for (int rt=0;rt<4;++rt) {
          int off = (rt*16 + l15)*512 + ks2*64 + g*16;
          pf[rt] = *(const bf16x8*)(smem + off);
        }
        int vb = krv*WXB + kcb*2 + laneV;
        bf16x8 vf[7];
#pragma unroll
        for (int et=0;et<7;++et)
          vf[et] = *(const bf16x8*)(g8B + vb + et*EPLANE);
#pragma unroll
        for (int rt=0;rt<4;++rt)
#pragma unroll
          for (int et=0;et<7;++et)
            acc[rt][et] = __builtin_amdgcn_mfma_f32_16x16x32_bf16(pf[rt], vf[et], acc[rt][et], 0,0,0);
      }
    }
    __syncthreads();                               // protect P for next iter
  }
  if (w < 7) {
    float* accB = accP + ((size_t)(chunk*2 + b)*1024)*784;
#pragma unroll
    for (int rt=0;rt<4;++rt)
#pragma unroll
      for (int et=0;et<7;++et)
#pragma unroll
        for (int r=0;r<4;++r)
          accB[(size_t)(q0 + rt*16 + g*4 + r)*784 + (w*7+et)*16 + l15] = acc[rt][et][r];
  }
}

// ---------------------------------------------------------------------------
// Sum partial accs over chunks, divide by l -> yvf[b*1024+q][784] fp32
// ---------------------------------------------------------------------------
__global__ void k_comb2(const float* __restrict__ accP, const float* __restrict__ lG,
                        float* __restrict__ yvf, int nch)
{
  int idx = blockIdx.x*256 + threadIdx.x;
  if (idx >= 2048*196) return;
  int bq = idx / 196, f4 = idx % 196;
  float4 s = {0.f,0.f,0.f,0.f};
  for (int c=0;c<nch;++c) {
    float4 v = *(const float4*)(accP + ((size_t)(c*2048 + bq))*784 + f4*4);
    s.x += v.x; s.y += v.y; s.z += v.z; s.w += v.w;
  }
  float inv = 1.0f / lG[bq];
  s.x*=inv; s.y*=inv; s.z*=inv; s.w*=inv;
  *(float4*)(yvf + (size_t)bq*784 + f4*4) = s;
}

// ---------------------------------------------------------------------------
// fold (stride-4, pad 3) + /mask -> y_cl[b][i][j][48]
// ---------------------------------------------------------------------------
template<int SC>
__global__ void k_fold_f32(const float* __restrict__ yvf, float* __restrict__ ycl)
{
  int idx = blockIdx.x*256 + threadIdx.x;
  if (idx >= 2*128*128) return;
  int j = idx & 127; int t = idx >> 7; int i = t & 127; int b = t >> 7;
  float a[16];
#pragma unroll
  for (int c=0;c<16;++c) a[c]=0.f;
  const float* yb = yvf + (size_t)b*1024*784;

  int drs[2], qis[2], cnti=0;
  int dcs[2], qjs[2], cntj=0;
#pragma unroll
  for (int dr=0; dr<7; ++dr) {
    int tr = i + 3 - dr;
    if (tr >= 0 && (tr & 3) == 0 && (tr >> 2) < 32) { drs[cnti]=dr; qis[cnti]=tr>>2; ++cnti; }
  }
#pragma unroll
  for (int dc=0; dc<7; ++dc) {
    int tc = j + 3 - dc;
    if (tc >= 0 && (tc & 3) == 0 && (tc >> 2) < 32) { dcs[cntj]=dc; qjs[cntj]=tc>>2; ++cntj; }
  }
  for (int u=0; u<cnti; ++u) {
    for (int v=0; v<cntj; ++v) {
      const float* src = yb + (size_t)(qis[u]*32 + qjs[v])*784 + (drs[u]*7 + dcs[v])*16;
      float4 v0 = *(const float4*)(src);
      float4 v1 = *(const float4*)(src+4);
      float4 v2 = *(const float4*)(src+8);
      float4 v3 = *(const float4*)(src+12);
      a[0]+=v0.x; a[1]+=v0.y; a[2]+=v0.z; a[3]+=v0.w;
      a[4]+=v1.x; a[5]+=v1.y; a[6]+=v1.z; a[7]+=v1.w;
      a[8]+=v2.x; a[9]+=v2.y; a[10]+=v2.z; a[11]+=v2.w;
      a[12]+=v3.x; a[13]+=v3.y; a[14]+=v3.z; a[15]+=v3.w;
    }
  }
  float inv = 1.0f / (float)(cnti*cntj);
  float* dst = ycl + (size_t)idx*48 + SC*16;
#pragma unroll
  for (int c=0;c<16;++c) dst[c] = a[c]*inv;
}

// ---------------------------------------------------------------------------
// out = conv1x1(y, w_out) + b_out + x
// ---------------------------------------------------------------------------
__global__ void k_final(const float* __restrict__ ycl, const float* __restrict__ wo,
                        const float* __restrict__ bo, const float* __restrict__ x,
                        float* __restrict__ out)
{
  __shared__ float wl[64*48];
  for (int t = threadIdx.x; t < 64*48; t += 256) wl[t] = wo[t];
  __syncthreads();
  int idx = blockIdx.x*256 + threadIdx.x;
  if (idx >= 2*128*128) return;
  int j = idx & 127; int t = idx >> 7; int i = t & 127; int b = t >> 7;
  float y[48];
  const float* ys = ycl + (size_t)idx*48;
#pragma unroll
  for (int c=0;c<48;++c) y[c] = ys[c];
  const float* xb = x + (size_t)b*64*16384 + i*128 + j;
  float* ob = out + (size_t)b*64*16384 + i*128 + j;
  for (int o=0;o<64;++o) {
    float s = bo[o];
#pragma unroll
    for (int c=0;c<48;++c) s += y[c]*wl[o*48+c];
    ob[(size_t)o*16384] = s + xb[(size_t)o*16384];
  }
}

// ---------------------------------------------------------------------------
extern "C" void kernel_launch(void* const* d_in, const int* in_sizes, int n_in,
                              void* d_out, int out_size, void* d_ws, size_t ws_size,
                              hipStream_t stream)
{
  const float* x  = (const float*)d_in[0];
  const float* wt = (const float*)d_in[1];
  const float* bt = (const float*)d_in[2];
  const float* wp0= (const float*)d_in[3];
  const float* bp0= (const float*)d_in[4];
  const float* wg0= (const float*)d_in[5];
  const float* bg0= (const float*)d_in[6];
  const float* wp1= (const float*)d_in[7];
  const float* bp1= (const float*)d_in[8];
  const float* wg1= (const float*)d_in[9];
  const float* bg1= (const float*)d_in[10];
  const float* wp2= (const float*)d_in[11];
  const float* bp2= (const float*)d_in[12];
  const float* wg2= (const float*)d_in[13];
  const float* bg2= (const float*)d_in[14];
  const float* wo = (const float*)d_in[15];
  const float* bo = (const float*)d_in[16];
  float* out = (float*)d_out;

  char* ws = (char*)d_ws;
  size_t off = 0;
  auto alloc = [&](size_t bytes)->char* { char* p = ws + off; off += (bytes + 255) & ~(size_t)255; return p; };
  unsigned short* th  = (unsigned short*)alloc(2ull*134*136*16*2);
  unsigned short* ph0 = (unsigned short*)alloc(2ull*134*136*16*2);
  unsigned short* ph1 = (unsigned short*)alloc(2ull*70*72*16*2);
  unsigned short* ph2 = (unsigned short*)alloc(2ull*38*40*16*2);
  float* gt0 = (float*)alloc(2ull*16*134*136*4);
  float* gt1 = (float*)alloc(2ull*16*70*72*4);
  float* gt2 = (float*)alloc(2ull*16*38*40*4);
  size_t zeroBytes = off;                      // th..gt2 contiguous prefix
  unsigned short* g80 = (unsigned short*)alloc(2ull*8*16*134*136*2);
  unsigned short* g81 = (unsigned short*)alloc(2ull*8*16*70*72*2);
  unsigned short* g82 = (unsigned short*)alloc(2ull*8*16*38*40*2);
  float* wT4 = (float*)alloc(1024ull*32*4);
  float* mP  = (float*)alloc(8ull*2048*4);
  float* lP  = (float*)alloc(8ull*2048*4);
  float* mG  = (float*)alloc(2048*4);
  float* lG  = (float*)alloc(2048*4);
  float* accP= (float*)alloc(8ull*2048*784*4);
  float* yvf = (float*)alloc(2048ull*784*4);
  float* ycl = (float*)alloc(2ull*128*128*48*4);
  (void)ws_size; (void)in_sizes; (void)n_in; (void)out_size;

  hipMemsetAsync(ws, 0, zeroBytes, stream);    // zero padded borders of th/ph/gt

  k_prep1<<<512,256,0,stream>>>(x, wt,bt, wp0,bp0, wg0,bg0, th, ph0, gt0);
  k_conv2<<<128,256,0,stream>>>(x, wp1,bp1, wg1,bg1, ph1, gt1);
  k_wt4<<<128,256,0,stream>>>(wp2, wg2, wT4);
  k_conv4<<<256,256,0,stream>>>(x, wT4, bp2, bg2, ph2, gt2);
  k_shift<134,136><<<(2*8*16*134*17+255)/256,256,0,stream>>>(gt0, g80);
  k_shift<70,72>  <<<(2*8*16*70*9 +255)/256,256,0,stream>>>(gt1, g81);
  k_shift<38,40>  <<<(2*8*16*38*5 +255)/256,256,0,stream>>>(gt2, g82);

  const int CB2 = (2048*196 + 255)/256;
  // ---- scale 0 (s=1): 16384 keys, 8 chunks of 2048 ----
  k_stats<128,7,134,136,2048><<<dim3(16,2,8),256,0,stream>>>(th, ph0, mP, lP);
  k_comb1<<<8,256,0,stream>>>(mP, lP, mG, lG, 8);
  k_pv<128,7,134,136,2048><<<dim3(16,2,8),512,0,stream>>>(th, ph0, g80, mG, accP);
  k_comb2<<<CB2,256,0,stream>>>(accP, lG, yvf, 8);
  k_fold_f32<0><<<128,256,0,stream>>>(yvf, ycl);
  // ---- scale 1 (s=2): 4096 keys, 2 chunks of 2048 ----
  k_stats<64,6,70,72,2048><<<dim3(16,2,2),256,0,stream>>>(th, ph1, mP, lP);
  k_comb1<<<8,256,0,stream>>>(mP, lP, mG, lG, 2);
  k_pv<64,6,70,72,2048><<<dim3(16,2,2),512,0,stream>>>(th, ph1, g81, mG, accP);
  k_comb2<<<CB2,256,0,stream>>>(accP, lG, yvf, 2);
  k_fold_f32<1><<<128,256,0,stream>>>(yvf, ycl);
  // ---- scale 2 (s=4): 1024 keys, 1 chunk ----
  k_stats<32,5,38,40,1024><<<dim3(16,2,1),256,0,stream>>>(th, ph2, mP, lP);
  k_comb1<<<8,256,0,stream>>>(mP, lP, mG, lG, 1);
  k_pv<32,5,38,40,1024><<<dim3(16,2,1),512,0,stream>>>(th, ph2, g82, mG, accP);
  k_comb2<<<CB2,256,0,stream>>>(accP, lG, yvf, 1);
  k_fold_f32<2><<<128,256,0,stream>>>(yvf, ycl);

  k_final<<<128,256,0,stream>>>(ycl, wo, bo, x, out);
}

// Round 7
// 899.275 us; speedup vs baseline: 13.7284x; 2.0101x over previous
//
#include <hip/hip_runtime.h>
#include <stdint.h>

typedef __attribute__((ext_vector_type(8))) short bf16x8;
typedef __attribute__((ext_vector_type(4))) float f32x4;

#define DEV __device__ __forceinline__

DEV float bf2f(unsigned short u){ union{unsigned int i; float f;} v; v.i=((unsigned int)u)<<16; return v.f; }
DEV unsigned short f2bf(float f){ union{float f; unsigned int i;} v; v.f=f; unsigned int x=v.i;
  return (unsigned short)((x + 0x7fffu + ((x>>16)&1u)) >> 16); }

// ---------------------------------------------------------------------------
// Fused s=1 prep: theta = (W_t x + b_t)*10*log2(e)  [bf16 CL padded 134x136x16]
//                 phi0  = W_p x + b_p               [bf16 CL padded]
//                 g0    = W_g x + b_g               [f32 CF padded 16x134x136]
// ---------------------------------------------------------------------------
__global__ void k_prep1(const float* __restrict__ x,
                        const float* __restrict__ wt, const float* __restrict__ bt,
                        const float* __restrict__ wp, const float* __restrict__ bp,
                        const float* __restrict__ wg, const float* __restrict__ bg,
                        unsigned short* __restrict__ th, unsigned short* __restrict__ ph,
                        float* __restrict__ gt)
{
  __shared__ float red[3][64][48];
  int tid = threadIdx.x;
  int grp = tid >> 6, pixl = tid & 63;
  int pix = blockIdx.x*64 + pixl;          // [0, 32768)
  int b = pix >> 14, p = pix & 16383, i = p >> 7, j = p & 127;
  float a[48];
#pragma unroll
  for (int c=0;c<48;++c) a[c]=0.f;
  const float* xb = x + (size_t)b*64*16384 + p;
#pragma unroll
  for (int c4=0; c4<4; ++c4) {
    int cc = grp*16 + c4*4;
    float xv[4];
#pragma unroll
    for (int u=0;u<4;++u) xv[u] = xb[(size_t)(cc+u)*16384];
#pragma unroll
    for (int ic=0;ic<16;++ic) {
      float4 w0 = *(const float4*)(wt + ic*64 + cc);
      float4 w1 = *(const float4*)(wp + ic*64 + cc);
      float4 w2 = *(const float4*)(wg + ic*64 + cc);
      a[ic]    += xv[0]*w0.x + xv[1]*w0.y + xv[2]*w0.z + xv[3]*w0.w;
      a[16+ic] += xv[0]*w1.x + xv[1]*w1.y + xv[2]*w1.z + xv[3]*w1.w;
      a[32+ic] += xv[0]*w2.x + xv[1]*w2.y + xv[2]*w2.z + xv[3]*w2.w;
    }
  }
  if (grp) {
#pragma unroll
    for (int c=0;c<48;++c) red[grp-1][pixl][c] = a[c];
  }
  __syncthreads();
  if (grp == 0) {
#pragma unroll
    for (int c=0;c<48;++c) a[c] += red[0][pixl][c] + red[1][pixl][c] + red[2][pixl][c];
    const float TEMPC = 14.426950408889634f;
    unsigned short o[16];
#pragma unroll
    for (int ic=0;ic<16;++ic) o[ic] = f2bf((a[ic]+bt[ic])*TEMPC);
    uint4* d0 = (uint4*)(th + ((size_t)(b*134 + i+3)*136 + (j+3))*16);
    d0[0]=*(uint4*)&o[0]; d0[1]=*(uint4*)&o[8];
#pragma unroll
    for (int ic=0;ic<16;++ic) o[ic] = f2bf(a[16+ic]+bp[ic]);
    uint4* d1 = (uint4*)(ph + ((size_t)(b*134 + i+3)*136 + (j+3))*16);
    d1[0]=*(uint4*)&o[0]; d1[1]=*(uint4*)&o[8];
#pragma unroll
    for (int ic=0;ic<16;++ic)
      gt[(((size_t)b*16+ic)*134 + i+3)*136 + (j+3)] = a[32+ic]+bg[ic];
  }
}

// ---------------------------------------------------------------------------
// s=2 conv: phi1 (bf16 CL padded 70x72x16), g1 (f32 CF padded 16x70x72)
// ---------------------------------------------------------------------------
__global__ void k_conv2(const float* __restrict__ x,
                        const float* __restrict__ wp, const float* __restrict__ bp,
                        const float* __restrict__ wg, const float* __restrict__ bg,
                        unsigned short* __restrict__ phi, float* __restrict__ gt)
{
  __shared__ float red[3][64][32];
  int tid = threadIdx.x;
  int grp = tid >> 6, pixl = tid & 63;
  int pix = blockIdx.x*64 + pixl;          // [0, 8192)
  int b = pix >> 12, p = pix & 4095, i = p >> 6, j = p & 63;
  float a[32];
#pragma unroll
  for (int c=0;c<32;++c) a[c]=0.f;
  const float* xb = x + (size_t)b*64*16384 + (i*2)*128 + j*2;
#pragma unroll
  for (int c0=0; c0<16; ++c0) {
    int cc = grp*16 + c0;
    const float* xp = xb + (size_t)cc*16384;
    float xv[4];
    xv[0]=xp[0]; xv[1]=xp[1]; xv[2]=xp[128]; xv[3]=xp[129];
#pragma unroll
    for (int ic=0;ic<16;++ic) {
      float4 w0 = *(const float4*)(wp + (ic*64+cc)*4);
      float4 w1 = *(const float4*)(wg + (ic*64+cc)*4);
      a[ic]    += xv[0]*w0.x + xv[1]*w0.y + xv[2]*w0.z + xv[3]*w0.w;
      a[16+ic] += xv[0]*w1.x + xv[1]*w1.y + xv[2]*w1.z + xv[3]*w1.w;
    }
  }
  if (grp) {
#pragma unroll
    for (int c=0;c<32;++c) red[grp-1][pixl][c] = a[c];
  }
  __syncthreads();
  if (grp == 0) {
#pragma unroll
    for (int c=0;c<32;++c) a[c] += red[0][pixl][c] + red[1][pixl][c] + red[2][pixl][c];
    unsigned short o[16];
#pragma unroll
    for (int ic=0;ic<16;++ic) o[ic] = f2bf(a[ic]+bp[ic]);
    uint4* d1 = (uint4*)(phi + ((size_t)(b*70 + i+3)*72 + (j+3))*16);
    d1[0]=*(uint4*)&o[0]; d1[1]=*(uint4*)&o[8];
#pragma unroll
    for (int ic=0;ic<16;++ic)
      gt[(((size_t)b*16+ic)*70 + i+3)*72 + (j+3)] = a[16+ic]+bg[ic];
  }
}

// ---------------------------------------------------------------------------
// Transpose s=4 weights: wT[k][32], k = cc*16 + a*4 + bb; c<16 phi, else g
// ---------------------------------------------------------------------------
__global__ void k_wt4(const float* __restrict__ wp, const float* __restrict__ wg,
                      float* __restrict__ wT)
{
  int idx = blockIdx.x*256 + threadIdx.x;
  if (idx >= 1024*32) return;
  int k = idx >> 5, c = idx & 31;
  int cc = k >> 4, ksp = k & 15;
  float v = (c < 16) ? wp[(c*64+cc)*16 + ksp] : wg[((c-16)*64+cc)*16 + ksp];
  wT[idx] = v;
}

// ---------------------------------------------------------------------------
// s=4 conv: 8 pixels x 32 out-channels; x patches staged in LDS
// ---------------------------------------------------------------------------
__global__ void k_conv4(const float* __restrict__ x, const float* __restrict__ wT,
                        const float* __restrict__ bp, const float* __restrict__ bg,
                        unsigned short* __restrict__ phi, float* __restrict__ gt)
{
  __shared__ float xs[8][1028];
  int tid = threadIdx.x;
  int pix0 = blockIdx.x*8;                 // [0,2048) step 8
  for (int idx = tid; idx < 8*1024; idx += 256) {
    int pl = idx >> 10, e = idx & 1023;
    int pix = pix0 + pl; int b = pix >> 10, p = pix & 1023, i = p >> 5, j = p & 31;
    int cc = e >> 4, a_ = (e >> 2) & 3, bb = e & 3;
    xs[pl][e] = x[(((size_t)b*64+cc)*128 + i*4+a_)*128 + j*4+bb];
  }
  __syncthreads();
  int pp = tid >> 5, icp = tid & 31;
  int pix = pix0 + pp; int b = pix >> 10, p = pix & 1023, i = p >> 5, j = p & 31;
  float acc = 0.f;
#pragma unroll 8
  for (int k4=0; k4<256; ++k4) {
    float4 xv = *(const float4*)(&xs[pp][k4*4]);
    acc += xv.x*wT[(k4*4  )*32+icp] + xv.y*wT[(k4*4+1)*32+icp]
         + xv.z*wT[(k4*4+2)*32+icp] + xv.w*wT[(k4*4+3)*32+icp];
  }
  int ic = icp & 15;
  if (icp < 16)
    phi[(((size_t)(b*38 + i+3)*40) + (j+3))*16 + ic] = f2bf(acc + bp[ic]);
  else
    gt[(((size_t)b*16+ic)*38 + i+3)*40 + (j+3)] = acc + bg[ic];
}

// ---------------------------------------------------------------------------
// g8[b][sh][c][y][x] = g_pad[b][c][y][x+sh]
// ---------------------------------------------------------------------------
template<int HP, int WX>
__global__ void k_shift(const float* __restrict__ gt, unsigned short* __restrict__ g8)
{
  const int WX8 = WX/8;
  int idx = blockIdx.x*256 + threadIdx.x;
  const int TOT = 2*8*16*HP*WX8;
  if (idx >= TOT) return;
  int x8 = idx % WX8; int t = idx/WX8; int y = t % HP; t/=HP;
  int c = t%16; t/=16; int sh = t%8; int b = t/8;
  const float* src = gt + (((size_t)b*16+c)*HP + y)*WX;
  unsigned short o[8];
#pragma unroll
  for (int jj=0;jj<8;++jj) {
    int xx = x8*8 + sh + jj;
    float v = (xx < WX) ? src[xx] : 0.f;
    o[jj]=f2bf(v);
  }
  *(uint4*)(g8 + ((((size_t)b*8+sh)*16+c)*HP + y)*(size_t)WX + x8*8) = *(uint4*)&o[0];
}

// ---------------------------------------------------------------------------
// Fused flash attention over one key-chunk. 8 waves, Q-tile 64, 256 keys/iter.
// Cross-wave online softmax (round-0 protocol, validated): QK -> tile max ->
// wave0 merge (m, alpha) -> P=exp2(sc-m) to XOR-swizzled P-LDS + rowsum ->
// waves 0-6 rescale+PV (e-chunks p=7w..7w+6 from shifted g8), wave7 updates l.
// Emits unnormalized partial acc + per-q (m_chunk, l_chunk).
// ---------------------------------------------------------------------------
template<int HS, int LG, int HP, int WX, int CK>
__global__ void __launch_bounds__(512, 2)
k_attn(const unsigned short* __restrict__ th, const unsigned short* __restrict__ phi,
       const unsigned short* __restrict__ g8, float* __restrict__ accP,
       float* __restrict__ mP, float* __restrict__ lP)
{
  __shared__ __align__(16) char smem[38400];
  const int PO = 0;          // P: 64 q x 256 k bf16 = 32768
  float* smm  = (float*)(smem + 32768);  // [64][9] tile max
  float* sms  = (float*)(smem + 35072);  // [64][9] tile sumexp
  float* mrun = (float*)(smem + 37376);  // [64]
  float* lrun = (float*)(smem + 37632);  // [64]
  float* mnew = (float*)(smem + 37888);  // [64]
  float* alph = (float*)(smem + 38144);  // [64]

  int tid = threadIdx.x;
  int w = tid >> 6, lane = tid & 63, l15 = lane & 15, g = lane >> 4;
  int b = blockIdx.y;
  int chunk = blockIdx.z;
  int q0 = blockIdx.x * 64;          // [0,1024)
  int qi0 = q0 >> 5;

  if (tid < 64) { mrun[tid] = -3.0e38f; lrun[tid] = 0.f; }
  __syncthreads();

  f32x4 acc[4][7];
#pragma unroll
  for (int rt=0;rt<4;++rt)
#pragma unroll
    for (int et=0;et<7;++et) acc[rt][et] = f32x4{0.f,0.f,0.f,0.f};

  const char* thB  = (const char*)th  + (size_t)b*134*136*32;
  const char* phiB = (const char*)phi + (size_t)b*HP*WX*32;
  const char* g8B  = (const char*)g8  + (size_t)b*8*16*HP*WX*2;
  const int CPLANE = HP*WX*2, EPLANE = 16*HP*WX*2, WXB = WX*2;
  int laneV = l15*CPLANE + g*16 + w*WXB;
  int xrP = (l15 & 7) << 4;                        // P-lds read swizzle
  int tb = ((4*qi0+2)*136 + 4*l15 + 2)*32 + ((g&1)<<4);
  const int OFFRT[4] = {0, 64*32, 4*136*32, 4*136*32 + 64*32};
  const bf16x8 ZV = {0,0,0,0,0,0,0,0};
  const int ITERS = CK/256;

#pragma unroll 1
  for (int it = 0; it < ITERS; ++it) {
    int k0 = chunk*CK + it*256;
    asm volatile("" : "+v"(tb));
    // ---------------- QK ----------------
    f32x4 sc[4][2];
#pragma unroll
    for (int rt=0;rt<4;++rt){ sc[rt][0]=f32x4{0.f,0.f,0.f,0.f}; sc[rt][1]=f32x4{0.f,0.f,0.f,0.f}; }
    int kr_w = (k0 + w*32) >> LG;
    int kc_w = (w*32) & (HS-1);
    int base0 = (kr_w*WX + kc_w + l15)*32 + ((g&1)<<4);
    int base1 = base0 + 512;
#pragma unroll
    for (int ks=0; ks<25; ++ks) {
      int p0 = 2*ks;
      int p1 = (2*ks+1 > 48) ? 48 : 2*ks+1;
      int KA0 = ((p0/7)*136 + (p0%7))*32;
      int KA1 = ((p1/7)*136 + (p1%7))*32;
      int KB0 = ((p0/7)*WX  + (p0%7))*32;
      int KB1 = ((p1/7)*WX  + (p1%7))*32;
      int selA = (g & 2) ? KA1 : KA0;
      int selB = (g & 2) ? KB1 : KB0;
      bf16x8 a0 = *(const bf16x8*)(thB + tb + selA + OFFRT[0]);
      bf16x8 a1 = *(const bf16x8*)(thB + tb + selA + OFFRT[1]);
      bf16x8 a2 = *(const bf16x8*)(thB + tb + selA + OFFRT[2]);
      bf16x8 a3 = *(const bf16x8*)(thB + tb + selA + OFFRT[3]);
      if (ks == 24) {
        bool z = (g & 2) != 0;
        a0 = z ? ZV : a0; a1 = z ? ZV : a1; a2 = z ? ZV : a2; a3 = z ? ZV : a3;
      }
      bf16x8 b0 = *(const bf16x8*)(phiB + base0 + selB);
      bf16x8 b1 = *(const bf16x8*)(phiB + base1 + selB);
      sc[0][0] = __builtin_amdgcn_mfma_f32_16x16x32_bf16(a0, b0, sc[0][0], 0,0,0);
      sc[0][1] = __builtin_amdgcn_mfma_f32_16x16x32_bf16(a0, b1, sc[0][1], 0,0,0);
      sc[1][0] = __builtin_amdgcn_mfma_f32_16x16x32_bf16(a1, b0, sc[1][0], 0,0,0);
      sc[1][1] = __builtin_amdgcn_mfma_f32_16x16x32_bf16(a1, b1, sc[1][1], 0,0,0);
      sc[2][0] = __builtin_amdgcn_mfma_f32_16x16x32_bf16(a2, b0, sc[2][0], 0,0,0);
      sc[2][1] = __builtin_amdgcn_mfma_f32_16x16x32_bf16(a2, b1, sc[2][1], 0,0,0);
      sc[3][0] = __builtin_amdgcn_mfma_f32_16x16x32_bf16(a3, b0, sc[3][0], 0,0,0);
      sc[3][1] = __builtin_amdgcn_mfma_f32_16x16x32_bf16(a3, b1, sc[3][1], 0,0,0);
    }
    // ---------------- tile max -> stats ----------------
    float tm[4][4];
#pragma unroll
    for (int rt=0;rt<4;++rt)
#pragma unroll
      for (int r=0;r<4;++r) tm[rt][r] = fmaxf(sc[rt][0][r], sc[rt][1][r]);
#pragma unroll
    for (int st=1; st<16; st<<=1)
#pragma unroll
      for (int rt=0;rt<4;++rt)
#pragma unroll
        for (int r=0;r<4;++r) tm[rt][r] = fmaxf(tm[rt][r], __shfl_xor(tm[rt][r], st));
    if (l15 == 0) {
#pragma unroll
      for (int rt=0;rt<4;++rt)
#pragma unroll
        for (int r=0;r<4;++r) smm[(rt*16 + g*4 + r)*9 + w] = tm[rt][r];
    }
    __syncthreads();                               // B1
    if (w == 0) {
      float mo = mrun[lane];
      float mx = smm[lane*9+0];
#pragma unroll
      for (int jj=1;jj<8;++jj) mx = fmaxf(mx, smm[lane*9+jj]);
      float mn = fmaxf(mo, mx);
      mrun[lane] = mn; mnew[lane] = mn;
      alph[lane] = __builtin_amdgcn_exp2f(mo - mn);
    }
    __syncthreads();                               // B2
    // ---------------- P = exp2(S - m), write P_lds, rowsum ----------------
    float mn_r[4][4];
#pragma unroll
    for (int rt=0;rt<4;++rt)
#pragma unroll
      for (int r=0;r<4;++r) mn_r[rt][r] = mnew[rt*16+g*4+r];
    float rs[4][4];
#pragma unroll
    for (int rt=0;rt<4;++rt) {
#pragma unroll
      for (int r=0;r<4;++r) {
        float pa = __builtin_amdgcn_exp2f(sc[rt][0][r] - mn_r[rt][r]);
        float pb = __builtin_amdgcn_exp2f(sc[rt][1][r] - mn_r[rt][r]);
        rs[rt][r] = pa + pb;
        int q_ = rt*16 + g*4 + r;
        int offa = q_*512 + (w*32 + l15)*2;      offa ^= (q_&7)<<4;
        int offb = q_*512 + (w*32 + 16 + l15)*2; offb ^= (q_&7)<<4;
        *(unsigned short*)(smem + PO + offa) = f2bf(pa);
        *(unsigned short*)(smem + PO + offb) = f2bf(pb);
      }
    }
#pragma unroll
    for (int st=1; st<16; st<<=1)
#pragma unroll
      for (int rt=0;rt<4;++rt)
#pragma unroll
        for (int r=0;r<4;++r) rs[rt][r] += __shfl_xor(rs[rt][r], st);
    if (l15 == 0) {
#pragma unroll
      for (int rt=0;rt<4;++rt)
#pragma unroll
        for (int r=0;r<4;++r) sms[(rt*16 + g*4 + r)*9 + w] = rs[rt][r];
    }
    __syncthreads();                               // B3
    // ---------------- PV / denominator update ----------------
    if (w == 7) {
      float ssum = sms[lane*9+0];
#pragma unroll
      for (int jj=1;jj<8;++jj) ssum += sms[lane*9+jj];
      lrun[lane] = lrun[lane]*alph[lane] + ssum;
    } else {
      float al[4][4];
#pragma unroll
      for (int rt=0;rt<4;++rt)
#pragma unroll
        for (int r=0;r<4;++r) al[rt][r] = alph[rt*16+g*4+r];
#pragma unroll
      for (int rt=0;rt<4;++rt)
#pragma unroll
        for (int et=0;et<7;++et)
#pragma unroll
          for (int r=0;r<4;++r) acc[rt][et][r] *= al[rt][r];
#pragma unroll
      for (int ks2=0; ks2<8; ++ks2) {
        int kk = k0 + ks2*32;
        int krv = kk >> LG;
        int kcb = kk & (HS-1);
        bf16x8 pf[4];
#pragma unroll
        for (int rt=0;rt<4;++rt) {
          int off = (rt*16 + l15)*512 + ks2*64 + g*16;
          off ^= xrP;
          pf[rt] = *(const bf16x8*)(smem + PO + off);
        }
        int vb = krv*WXB + kcb*2 + laneV;
        bf16x8 vf[7];
#pragma unroll
        for (int et=0;et<7;++et)
          vf[et] = *(const bf16x8*)(g8B + vb + et*EPLANE);
#pragma unroll
        for (int rt=0;rt<4;++rt)
#pragma unroll
          for (int et=0;et<7;++et)
            acc[rt][et] = __builtin_amdgcn_mfma_f32_16x16x32_bf16(pf[rt], vf[et], acc[rt][et], 0,0,0);
      }
    }
  }
  __syncthreads();
  if (w < 7) {
    float* accB = accP + ((size_t)(chunk*2 + b)*1024)*784;
#pragma unroll
    for (int rt=0;rt<4;++rt)
#pragma unroll
      for (int et=0;et<7;++et)
#pragma unroll
        for (int r=0;r<4;++r)
          accB[(size_t)(q0 + rt*16 + g*4 + r)*784 + (w*7+et)*16 + l15] = acc[rt][et][r];
  }
  if (tid < 64) {
    size_t o = (size_t)(chunk*2 + b)*1024 + q0 + tid;
    mP[o] = mrun[tid];
    lP[o] = lrun[tid];
  }
}

// ---------------------------------------------------------------------------
// Merge per-chunk stats: mG = max, lG = sum l_c * 2^(m_c - mG)
// ---------------------------------------------------------------------------
__global__ void k_comb1(const float* __restrict__ mP, const float* __restrict__ lP,
                        float* __restrict__ mG, float* __restrict__ lG, int nch)
{
  int idx = blockIdx.x*256 + threadIdx.x;
  if (idx >= 2048) return;
  float m = -3.0e38f;
  for (int c=0;c<nch;++c) m = fmaxf(m, mP[c*2048 + idx]);
  float l = 0.f;
  for (int c=0;c<nch;++c) l += lP[c*2048 + idx] * exp2f(mP[c*2048 + idx] - m);
  mG[idx] = m; lG[idx] = l;
}

// ---------------------------------------------------------------------------
// Rescale partial accs by 2^(m_c - mG), sum over chunks, divide by lG
// ---------------------------------------------------------------------------
__global__ void k_comb2(const float* __restrict__ accP, const float* __restrict__ mP,
                        const float* __restrict__ mG, const float* __restrict__ lG,
                        float* __restrict__ yvf, int nch)
{
  int idx = blockIdx.x*256 + threadIdx.x;
  if (idx >= 2048*196) return;
  int bq = idx / 196, f4 = idx % 196;
  float mg = mG[bq];
  float4 s = {0.f,0.f,0.f,0.f};
  for (int c=0;c<nch;++c) {
    float f = exp2f(mP[c*2048 + bq] - mg);
    float4 v = *(const float4*)(accP + ((size_t)(c*2048 + bq))*784 + f4*4);
    s.x += v.x*f; s.y += v.y*f; s.z += v.z*f; s.w += v.w*f;
  }
  float inv = 1.0f / lG[bq];
  s.x*=inv; s.y*=inv; s.z*=inv; s.w*=inv;
  *(float4*)(yvf + (size_t)bq*784 + f4*4) = s;
}

// ---------------------------------------------------------------------------
// fold (stride-4, pad 3) + /mask -> y_cl[b][i][j][48]
// ---------------------------------------------------------------------------
template<int SC>
__global__ void k_fold_f32(const float* __restrict__ yvf, float* __restrict__ ycl)
{
  int idx = blockIdx.x*256 + threadIdx.x;
  if (idx >= 2*128*128) return;
  int j = idx & 127; int t = idx >> 7; int i = t & 127; int b = t >> 7;
  float a[16];
#pragma unroll
  for (int c=0;c<16;++c) a[c]=0.f;
  const float* yb = yvf + (size_t)b*1024*784;

  int drs[2], qis[2], cnti=0;
  int dcs[2], qjs[2], cntj=0;
#pragma unroll
  for (int dr=0; dr<7; ++dr) {
    int tr = i + 3 - dr;
    if (tr >= 0 && (tr & 3) == 0 && (tr >> 2) < 32) { drs[cnti]=dr; qis[cnti]=tr>>2; ++cnti; }
  }
#pragma unroll
  for (int dc=0; dc<7; ++dc) {
    int tc = j + 3 - dc;
    if (tc >= 0 && (tc & 3) == 0 && (tc >> 2) < 32) { dcs[cntj]=dc; qjs[cntj]=tc>>2; ++cntj; }
  }
  for (int u=0; u<cnti; ++u) {
    for (int v=0; v<cntj; ++v) {
      const float* src = yb + (size_t)(qis[u]*32 + qjs[v])*784 + (drs[u]*7 + dcs[v])*16;
      float4 v0 = *(const float4*)(src);
      float4 v1 = *(const float4*)(src+4);
      float4 v2 = *(const float4*)(src+8);
      float4 v3 = *(const float4*)(src+12);
      a[0]+=v0.x; a[1]+=v0.y; a[2]+=v0.z; a[3]+=v0.w;
      a[4]+=v1.x; a[5]+=v1.y; a[6]+=v1.z; a[7]+=v1.w;
      a[8]+=v2.x; a[9]+=v2.y; a[10]+=v2.z; a[11]+=v2.w;
      a[12]+=v3.x; a[13]+=v3.y; a[14]+=v3.z; a[15]+=v3.w;
    }
  }
  float inv = 1.0f / (float)(cnti*cntj);
  float* dst = ycl + (size_t)idx*48 + SC*16;
#pragma unroll
  for (int c=0;c<16;++c) dst[c] = a[c]*inv;
}

// ---------------------------------------------------------------------------
// out = conv1x1(y, w_out) + b_out + x
// ---------------------------------------------------------------------------
__global__ void k_final(const float* __restrict__ ycl, const float* __restrict__ wo,
                        const float* __restrict__ bo, const float* __restrict__ x,
                        float* __restrict__ out)
{
  __shared__ float wl[64*48];
  for (int t = threadIdx.x; t < 64*48; t += 256) wl[t] = wo[t];
  __syncthreads();
  int idx = blockIdx.x*256 + threadIdx.x;
  if (idx >= 2*128*128) return;
  int j = idx & 127; int t = idx >> 7; int i = t & 127; int b = t >> 7;
  float y[48];
  const float* ys = ycl + (size_t)idx*48;
#pragma unroll
  for (int c=0;c<48;++c) y[c] = ys[c];
  const float* xb = x + (size_t)b*64*16384 + i*128 + j;
  float* ob = out + (size_t)b*64*16384 + i*128 + j;
  for (int o=0;o<64;++o) {
    float s = bo[o];
#pragma unroll
    for (int c=0;c<48;++c) s += y[c]*wl[o*48+c];
    ob[(size_t)o*16384] = s + xb[(size_t)o*16384];
  }
}

// ---------------------------------------------------------------------------
extern "C" void kernel_launch(void* const* d_in, const int* in_sizes, int n_in,
                              void* d_out, int out_size, void* d_ws, size_t ws_size,
                              hipStream_t stream)
{
  const float* x  = (const float*)d_in[0];
  const float* wt = (const float*)d_in[1];
  const float* bt = (const float*)d_in[2];
  const float* wp0= (const float*)d_in[3];
  const float* bp0= (const float*)d_in[4];
  const float* wg0= (const float*)d_in[5];
  const float* bg0= (const float*)d_in[6];
  const float* wp1= (const float*)d_in[7];
  const float* bp1= (const float*)d_in[8];
  const float* wg1= (const float*)d_in[9];
  const float* bg1= (const float*)d_in[10];
  const float* wp2= (const float*)d_in[11];
  const float* bp2= (const float*)d_in[12];
  const float* wg2= (const float*)d_in[13];
  const float* bg2= (const float*)d_in[14];
  const float* wo = (const float*)d_in[15];
  const float* bo = (const float*)d_in[16];
  float* out = (float*)d_out;

  char* ws = (char*)d_ws;
  size_t off = 0;
  auto alloc = [&](size_t bytes)->char* { char* p = ws + off; off += (bytes + 255) & ~(size_t)255; return p; };
  unsigned short* th  = (unsigned short*)alloc(2ull*134*136*16*2);
  unsigned short* ph0 = (unsigned short*)alloc(2ull*134*136*16*2);
  unsigned short* ph1 = (unsigned short*)alloc(2ull*70*72*16*2);
  unsigned short* ph2 = (unsigned short*)alloc(2ull*38*40*16*2);
  float* gt0 = (float*)alloc(2ull*16*134*136*4);
  float* gt1 = (float*)alloc(2ull*16*70*72*4);
  float* gt2 = (float*)alloc(2ull*16*38*40*4);
  size_t zeroBytes = off;                      // th..gt2 contiguous prefix
  unsigned short* g80 = (unsigned short*)alloc(2ull*8*16*134*136*2);
  unsigned short* g81 = (unsigned short*)alloc(2ull*8*16*70*72*2);
  unsigned short* g82 = (unsigned short*)alloc(2ull*8*16*38*40*2);
  float* wT4 = (float*)alloc(1024ull*32*4);
  float* mP  = (float*)alloc(8ull*2048*4);
  float* lP  = (float*)alloc(8ull*2048*4);
  float* mG  = (float*)alloc(2048*4);
  float* lG  = (float*)alloc(2048*4);
  float* accP= (float*)alloc(8ull*2048*784*4);
  float* yvf = (float*)alloc(2048ull*784*4);
  float* ycl = (float*)alloc(2ull*128*128*48*4);
  (void)ws_size; (void)in_sizes; (void)n_in; (void)out_size;

  hipMemsetAsync(ws, 0, zeroBytes, stream);    // zero padded borders of th/ph/gt

  k_prep1<<<512,256,0,stream>>>(x, wt,bt, wp0,bp0, wg0,bg0, th, ph0, gt0);
  k_conv2<<<128,256,0,stream>>>(x, wp1,bp1, wg1,bg1, ph1, gt1);
  k_wt4<<<128,256,0,stream>>>(wp2, wg2, wT4);
  k_conv4<<<256,256,0,stream>>>(x, wT4, bp2, bg2, ph2, gt2);
  k_shift<134,136><<<(2*8*16*134*17+255)/256,256,0,stream>>>(gt0, g80);
  k_shift<70,72>  <<<(2*8*16*70*9 +255)/256,256,0,stream>>>(gt1, g81);
  k_shift<38,40>  <<<(2*8*16*38*5 +255)/256,256,0,stream>>>(gt2, g82);

  const int CB2 = (2048*196 + 255)/256;
  // ---- scale 0 (s=1): 16384 keys, 8 chunks of 2048 ----
  k_attn<128,7,134,136,2048><<<dim3(16,2,8),512,0,stream>>>(th, ph0, g80, accP, mP, lP);
  k_comb1<<<8,256,0,stream>>>(mP, lP, mG, lG, 8);
  k_comb2<<<CB2,256,0,stream>>>(accP, mP, mG, lG, yvf, 8);
  k_fold_f32<0><<<128,256,0,stream>>>(yvf, ycl);
  // ---- scale 1 (s=2): 4096 keys, 8 chunks of 512 ----
  k_attn<64,6,70,72,512><<<dim3(16,2,8),512,0,stream>>>(th, ph1, g81, accP, mP, lP);
  k_comb1<<<8,256,0,stream>>>(mP, lP, mG, lG, 8);
  k_comb2<<<CB2,256,0,stream>>>(accP, mP, mG, lG, yvf, 8);
  k_fold_f32<1><<<128,256,0,stream>>>(yvf, ycl);
  // ---- scale 2 (s=4): 1024 keys, 4 chunks of 256 ----
  k_attn<32,5,38,40,256><<<dim3(16,2,4),512,0,stream>>>(th, ph2, g82, accP, mP, lP);
  k_comb1<<<8,256,0,stream>>>(mP, lP, mG, lG, 4);
  k_comb2<<<CB2,256,0,stream>>>(accP, mP, mG, lG, yvf, 4);
  k_fold_f32<2><<<128,256,0,stream>>>(yvf, ycl);

  k_final<<<128,256,0,stream>>>(ycl, wo, bo, x, out);
}

// Round 9
// 785.224 us; speedup vs baseline: 15.7224x; 1.1452x over previous
//
#include <hip/hip_runtime.h>
#include <stdint.h>

typedef __attribute__((ext_vector_type(8))) short bf16x8;
typedef __attribute__((ext_vector_type(4))) float f32x4;

#define DEV __device__ __forceinline__

DEV float bf2f(unsigned short u){ union{unsigned int i; float f;} v; v.i=((unsigned int)u)<<16; return v.f; }
DEV unsigned short f2bf(float f){ union{float f; unsigned int i;} v; v.f=f; unsigned int x=v.i;
  return (unsigned short)((x + 0x7fffu + ((x>>16)&1u)) >> 16); }

// ---------------------------------------------------------------------------
// Fused s=1 prep: theta = (W_t x + b_t)*10*log2(e)  [bf16 CL padded 134x136x16]
//                 phi0  = W_p x + b_p               [bf16 CL padded]
//                 g0    = W_g x + b_g               [f32 CF padded 16x134x136]
// ---------------------------------------------------------------------------
__global__ void k_prep1(const float* __restrict__ x,
                        const float* __restrict__ wt, const float* __restrict__ bt,
                        const float* __restrict__ wp, const float* __restrict__ bp,
                        const float* __restrict__ wg, const float* __restrict__ bg,
                        unsigned short* __restrict__ th, unsigned short* __restrict__ ph,
                        float* __restrict__ gt)
{
  __shared__ float red[3][64][48];
  int tid = threadIdx.x;
  int grp = tid >> 6, pixl = tid & 63;
  int pix = blockIdx.x*64 + pixl;          // [0, 32768)
  int b = pix >> 14, p = pix & 16383, i = p >> 7, j = p & 127;
  float a[48];
#pragma unroll
  for (int c=0;c<48;++c) a[c]=0.f;
  const float* xb = x + (size_t)b*64*16384 + p;
#pragma unroll
  for (int c4=0; c4<4; ++c4) {
    int cc = grp*16 + c4*4;
    float xv[4];
#pragma unroll
    for (int u=0;u<4;++u) xv[u] = xb[(size_t)(cc+u)*16384];
#pragma unroll
    for (int ic=0;ic<16;++ic) {
      float4 w0 = *(const float4*)(wt + ic*64 + cc);
      float4 w1 = *(const float4*)(wp + ic*64 + cc);
      float4 w2 = *(const float4*)(wg + ic*64 + cc);
      a[ic]    += xv[0]*w0.x + xv[1]*w0.y + xv[2]*w0.z + xv[3]*w0.w;
      a[16+ic] += xv[0]*w1.x + xv[1]*w1.y + xv[2]*w1.z + xv[3]*w1.w;
      a[32+ic] += xv[0]*w2.x + xv[1]*w2.y + xv[2]*w2.z + xv[3]*w2.w;
    }
  }
  if (grp) {
#pragma unroll
    for (int c=0;c<48;++c) red[grp-1][pixl][c] = a[c];
  }
  __syncthreads();
  if (grp == 0) {
#pragma unroll
    for (int c=0;c<48;++c) a[c] += red[0][pixl][c] + red[1][pixl][c] + red[2][pixl][c];
    const float TEMPC = 14.426950408889634f;
    unsigned short o[16];
#pragma unroll
    for (int ic=0;ic<16;++ic) o[ic] = f2bf((a[ic]+bt[ic])*TEMPC);
    uint4* d0 = (uint4*)(th + ((size_t)(b*134 + i+3)*136 + (j+3))*16);
    d0[0]=*(uint4*)&o[0]; d0[1]=*(uint4*)&o[8];
#pragma unroll
    for (int ic=0;ic<16;++ic) o[ic] = f2bf(a[16+ic]+bp[ic]);
    uint4* d1 = (uint4*)(ph + ((size_t)(b*134 + i+3)*136 + (j+3))*16);
    d1[0]=*(uint4*)&o[0]; d1[1]=*(uint4*)&o[8];
#pragma unroll
    for (int ic=0;ic<16;++ic)
      gt[(((size_t)b*16+ic)*134 + i+3)*136 + (j+3)] = a[32+ic]+bg[ic];
  }
}

// ---------------------------------------------------------------------------
// s=2 conv: phi1 (bf16 CL padded 70x72x16), g1 (f32 CF padded 16x70x72)
// ---------------------------------------------------------------------------
__global__ void k_conv2(const float* __restrict__ x,
                        const float* __restrict__ wp, const float* __restrict__ bp,
                        const float* __restrict__ wg, const float* __restrict__ bg,
                        unsigned short* __restrict__ phi, float* __restrict__ gt)
{
  __shared__ float red[3][64][32];
  int tid = threadIdx.x;
  int grp = tid >> 6, pixl = tid & 63;
  int pix = blockIdx.x*64 + pixl;          // [0, 8192)
  int b = pix >> 12, p = pix & 4095, i = p >> 6, j = p & 63;
  float a[32];
#pragma unroll
  for (int c=0;c<32;++c) a[c]=0.f;
  const float* xb = x + (size_t)b*64*16384 + (i*2)*128 + j*2;
#pragma unroll
  for (int c0=0; c0<16; ++c0) {
    int cc = grp*16 + c0;
    const float* xp = xb + (size_t)cc*16384;
    float xv[4];
    xv[0]=xp[0]; xv[1]=xp[1]; xv[2]=xp[128]; xv[3]=xp[129];
#pragma unroll
    for (int ic=0;ic<16;++ic) {
      float4 w0 = *(const float4*)(wp + (ic*64+cc)*4);
      float4 w1 = *(const float4*)(wg + (ic*64+cc)*4);
      a[ic]    += xv[0]*w0.x + xv[1]*w0.y + xv[2]*w0.z + xv[3]*w0.w;
      a[16+ic] += xv[0]*w1.x + xv[1]*w1.y + xv[2]*w1.z + xv[3]*w1.w;
    }
  }
  if (grp) {
#pragma unroll
    for (int c=0;c<32;++c) red[grp-1][pixl][c] = a[c];
  }
  __syncthreads();
  if (grp == 0) {
#pragma unroll
    for (int c=0;c<32;++c) a[c] += red[0][pixl][c] + red[1][pixl][c] + red[2][pixl][c];
    unsigned short o[16];
#pragma unroll
    for (int ic=0;ic<16;++ic) o[ic] = f2bf(a[ic]+bp[ic]);
    uint4* d1 = (uint4*)(phi + ((size_t)(b*70 + i+3)*72 + (j+3))*16);
    d1[0]=*(uint4*)&o[0]; d1[1]=*(uint4*)&o[8];
#pragma unroll
    for (int ic=0;ic<16;++ic)
      gt[(((size_t)b*16+ic)*70 + i+3)*72 + (j+3)] = a[16+ic]+bg[ic];
  }
}

// ---------------------------------------------------------------------------
// Transpose s=4 weights: wT[k][32], k = cc*16 + a*4 + bb; c<16 phi, else g
// ---------------------------------------------------------------------------
__global__ void k_wt4(const float* __restrict__ wp, const float* __restrict__ wg,
                      float* __restrict__ wT)
{
  int idx = blockIdx.x*256 + threadIdx.x;
  if (idx >= 1024*32) return;
  int k = idx >> 5, c = idx & 31;
  int cc = k >> 4, ksp = k & 15;
  float v = (c < 16) ? wp[(c*64+cc)*16 + ksp] : wg[((c-16)*64+cc)*16 + ksp];
  wT[idx] = v;
}

// ---------------------------------------------------------------------------
// s=4 conv: 8 pixels x 32 out-channels; x patches staged in LDS
// ---------------------------------------------------------------------------
__global__ void k_conv4(const float* __restrict__ x, const float* __restrict__ wT,
                        const float* __restrict__ bp, const float* __restrict__ bg,
                        unsigned short* __restrict__ phi, float* __restrict__ gt)
{
  __shared__ float xs[8][1028];
  int tid = threadIdx.x;
  int pix0 = blockIdx.x*8;                 // [0,2048) step 8
  for (int idx = tid; idx < 8*1024; idx += 256) {
    int pl = idx >> 10, e = idx & 1023;
    int pix = pix0 + pl; int b = pix >> 10, p = pix & 1023, i = p >> 5, j = p & 31;
    int cc = e >> 4, a_ = (e >> 2) & 3, bb = e & 3;
    xs[pl][e] = x[(((size_t)b*64+cc)*128 + i*4+a_)*128 + j*4+bb];
  }
  __syncthreads();
  int pp = tid >> 5, icp = tid & 31;
  int pix = pix0 + pp; int b = pix >> 10, p = pix & 1023, i = p >> 5, j = p & 31;
  float acc = 0.f;
#pragma unroll 8
  for (int k4=0; k4<256; ++k4) {
    float4 xv = *(const float4*)(&xs[pp][k4*4]);
    acc += xv.x*wT[(k4*4  )*32+icp] + xv.y*wT[(k4*4+1)*32+icp]
         + xv.z*wT[(k4*4+2)*32+icp] + xv.w*wT[(k4*4+3)*32+icp];
  }
  int ic = icp & 15;
  if (icp < 16)
    phi[(((size_t)(b*38 + i+3)*40) + (j+3))*16 + ic] = f2bf(acc + bp[ic]);
  else
    gt[(((size_t)b*16+ic)*38 + i+3)*40 + (j+3)] = acc + bg[ic];
}

// ---------------------------------------------------------------------------
// g8[b][sh][c][y][x] = g_pad[b][c][y][x+sh]
// ---------------------------------------------------------------------------
template<int HP, int WX>
__global__ void k_shift(const float* __restrict__ gt, unsigned short* __restrict__ g8)
{
  const int WX8 = WX/8;
  int idx = blockIdx.x*256 + threadIdx.x;
  const int TOT = 2*8*16*HP*WX8;
  if (idx >= TOT) return;
  int x8 = idx % WX8; int t = idx/WX8; int y = t % HP; t/=HP;
  int c = t%16; t/=16; int sh = t%8; int b = t/8;
  const float* src = gt + (((size_t)b*16+c)*HP + y)*WX;
  unsigned short o[8];
#pragma unroll
  for (int jj=0;jj<8;++jj) {
    int xx = x8*8 + sh + jj;
    float v = (xx < WX) ? src[xx] : 0.f;
    o[jj]=f2bf(v);
  }
  *(uint4*)(g8 + ((((size_t)b*8+sh)*16+c)*HP + y)*(size_t)WX + x8*8) = *(uint4*)&o[0];
}

// ---------------------------------------------------------------------------
// Flash attention with FIXED softmax shift (P = exp2(min(sc-64, 120))):
// exact after acc/l cancellation; clamp makes inf structurally impossible.
// Q-tile 32 (one stride-4 query row), 8 waves, 256 keys/iter, 2 barriers/iter.
// XCD-swizzled 1-D grid: chunk = bid&(NCH-1) so all q-tiles of a chunk share
// one XCD's L2. Per-lane l accumulates in regs; one shfl-reduce at the end.
// Partials directly summable across chunks (same shift everywhere).
// ---------------------------------------------------------------------------
template<int HS, int LG, int HP, int WX, int CK, int NCH>
__global__ void __launch_bounds__(512, 2)
k_attn(const unsigned short* __restrict__ th, const unsigned short* __restrict__ phi,
       const unsigned short* __restrict__ g8, float* __restrict__ accP,
       float* __restrict__ lP)
{
  __shared__ __align__(16) char smem[16384];   // P: 32 q x 256 k bf16

  int tid = threadIdx.x;
  int w = tid >> 6, lane = tid & 63, l15 = lane & 15, g = lane >> 4;
  int bid = blockIdx.x;
  int chunk, b, qt;
  if (NCH == 8) { chunk = bid & 7; b = (bid >> 3) & 1; qt = bid >> 4; }
  else          { chunk = bid & 3; b = (bid >> 2) & 1; qt = bid >> 3; }
  int q0 = qt * 32;

  f32x4 acc[2][7];
#pragma unroll
  for (int rt=0;rt<2;++rt)
#pragma unroll
    for (int et=0;et<7;++et) acc[rt][et] = f32x4{0.f,0.f,0.f,0.f};
  float lacc[2][4];
#pragma unroll
  for (int rt=0;rt<2;++rt)
#pragma unroll
    for (int r=0;r<4;++r) lacc[rt][r] = 0.f;

  const char* thB  = (const char*)th  + (size_t)b*134*136*32;
  const char* phiB = (const char*)phi + (size_t)b*HP*WX*32;
  const char* g8B  = (const char*)g8  + (size_t)b*8*16*HP*WX*2;
  const int CPLANE = HP*WX*2, EPLANE = 16*HP*WX*2, WXB = WX*2;
  int laneV = l15*CPLANE + g*16 + w*WXB;
  int xrP = (l15 & 7) << 4;                        // P-lds read swizzle
  int tb = ((4*qt+2)*136 + 4*l15 + 2)*32 + ((g&1)<<4);
  const bf16x8 ZV = {0,0,0,0,0,0,0,0};
  const int ITERS = CK/256;
  const float SHIFT = 64.0f, CLAMP = 120.0f;

#pragma unroll 1
  for (int it = 0; it < ITERS; ++it) {
    int k0 = chunk*CK + it*256;
    asm volatile("" : "+v"(tb));
    // ---------------- QK ----------------
    f32x4 sc[2][2];
#pragma unroll
    for (int rt=0;rt<2;++rt){ sc[rt][0]=f32x4{0.f,0.f,0.f,0.f}; sc[rt][1]=f32x4{0.f,0.f,0.f,0.f}; }
    int kr_w = (k0 + w*32) >> LG;
    int kc_w = (w*32) & (HS-1);
    int base0 = (kr_w*WX + kc_w + l15)*32 + ((g&1)<<4);
    int base1 = base0 + 512;
#pragma unroll
    for (int ks=0; ks<25; ++ks) {
      int p0 = 2*ks;
      int p1 = (2*ks+1 > 48) ? 48 : 2*ks+1;
      int KA0 = ((p0/7)*136 + (p0%7))*32;
      int KA1 = ((p1/7)*136 + (p1%7))*32;
      int KB0 = ((p0/7)*WX  + (p0%7))*32;
      int KB1 = ((p1/7)*WX  + (p1%7))*32;
      int selA = (g & 2) ? KA1 : KA0;
      int selB = (g & 2) ? KB1 : KB0;
      bf16x8 a0 = *(const bf16x8*)(thB + tb + selA);
      bf16x8 a1 = *(const bf16x8*)(thB + tb + selA + 2048);
      if (ks == 24) {
        bool z = (g & 2) != 0;
        a0 = z ? ZV : a0; a1 = z ? ZV : a1;
      }
      bf16x8 b0 = *(const bf16x8*)(phiB + base0 + selB);
      bf16x8 b1 = *(const bf16x8*)(phiB + base1 + selB);
      sc[0][0] = __builtin_amdgcn_mfma_f32_16x16x32_bf16(a0, b0, sc[0][0], 0,0,0);
      sc[0][1] = __builtin_amdgcn_mfma_f32_16x16x32_bf16(a0, b1, sc[0][1], 0,0,0);
      sc[1][0] = __builtin_amdgcn_mfma_f32_16x16x32_bf16(a1, b0, sc[1][0], 0,0,0);
      sc[1][1] = __builtin_amdgcn_mfma_f32_16x16x32_bf16(a1, b1, sc[1][1], 0,0,0);
    }
    // ---------------- P = exp2(min(S-64,120)), accumulate l, write P_lds ----------------
#pragma unroll
    for (int rt=0;rt<2;++rt) {
#pragma unroll
      for (int r=0;r<4;++r) {
        float pa = __builtin_amdgcn_exp2f(fminf(sc[rt][0][r] - SHIFT, CLAMP));
        float pb = __builtin_amdgcn_exp2f(fminf(sc[rt][1][r] - SHIFT, CLAMP));
        lacc[rt][r] += pa + pb;
        int q_ = rt*16 + g*4 + r;
        int offa = q_*512 + (w*32 + l15)*2;      offa ^= (q_&7)<<4;
        int offb = q_*512 + (w*32 + 16 + l15)*2; offb ^= (q_&7)<<4;
        *(unsigned short*)(smem + offa) = f2bf(pa);
        *(unsigned short*)(smem + offb) = f2bf(pb);
      }
    }
    __syncthreads();                               // P ready
    // ---------------- PV ----------------
    if (w < 7) {
#pragma unroll
      for (int ks2=0; ks2<8; ++ks2) {
        int kk = k0 + ks2*32;
        int krv = kk >> LG;
        int kcb = kk & (HS-1);
        bf16x8 pf[2];
#pragma unroll
        for (int rt=0;rt<2;++rt) {
          int off = (rt*16 + l15)*512 + ks2*64 + g*16;
          off ^= xrP;
          pf[rt] = *(const bf16x8*)(smem + off);
        }
        int vb = krv*WXB + kcb*2 + laneV;
        bf16x8 vf[7];
#pragma unroll
        for (int et=0;et<7;++et)
          vf[et] = *(const bf16x8*)(g8B + vb + et*EPLANE);
#pragma unroll
        for (int rt=0;rt<2;++rt)
#pragma unroll
          for (int et=0;et<7;++et)
            acc[rt][et] = __builtin_amdgcn_mfma_f32_16x16x32_bf16(pf[rt], vf[et], acc[rt][et], 0,0,0);
      }
    }
    __syncthreads();                               // protect P for next iter
  }
  if (w < 7) {
    float* accB = accP + ((size_t)(chunk*2 + b)*1024)*784;
#pragma unroll
    for (int rt=0;rt<2;++rt)
#pragma unroll
      for (int et=0;et<7;++et)
#pragma unroll
        for (int r=0;r<4;++r)
          accB[(size_t)(q0 + rt*16 + g*4 + r)*784 + (w*7+et)*16 + l15] = acc[rt][et][r];
  }
  // per-wave l partials: reduce over the 16-lane group, write one slot per wave
#pragma unroll
  for (int st=1; st<16; st<<=1)
#pragma unroll
    for (int rt=0;rt<2;++rt)
#pragma unroll
      for (int r=0;r<4;++r) lacc[rt][r] += __shfl_xor(lacc[rt][r], st);
  if (l15 == 0) {
#pragma unroll
    for (int rt=0;rt<2;++rt)
#pragma unroll
      for (int r=0;r<4;++r)
        lP[((size_t)((chunk*2 + b)*8 + w) << 10) + q0 + rt*16 + g*4 + r] = lacc[rt][r];
  }
}

// ---------------------------------------------------------------------------
// lG[b*1024+q] = sum over chunks and waves of lP
// ---------------------------------------------------------------------------
__global__ void k_comb1(const float* __restrict__ lP, float* __restrict__ lG, int nch)
{
  int idx = blockIdx.x*256 + threadIdx.x;
  if (idx >= 2048) return;
  int b = idx >> 10, q = idx & 1023;
  float l = 0.f;
  for (int c=0;c<nch;++c)
#pragma unroll
    for (int w=0;w<8;++w)
      l += lP[((size_t)((c*2 + b)*8 + w) << 10) + q];
  lG[idx] = l;
}

// ---------------------------------------------------------------------------
// Sum partial accs over chunks (directly summable, shared shift), / lG
// ---------------------------------------------------------------------------
__global__ void k_comb2(const float* __restrict__ accP, const float* __restrict__ lG,
                        float* __restrict__ yvf, int nch)
{
  int idx = blockIdx.x*256 + threadIdx.x;
  if (idx >= 2048*196) return;
  int bq = idx / 196, f4 = idx % 196;
  float4 s = {0.f,0.f,0.f,0.f};
  for (int c=0;c<nch;++c) {
    float4 v = *(const float4*)(accP + ((size_t)(c*2048 + bq))*784 + f4*4);
    s.x += v.x; s.y += v.y; s.z += v.z; s.w += v.w;
  }
  float inv = 1.0f / lG[bq];
  s.x*=inv; s.y*=inv; s.z*=inv; s.w*=inv;
  *(float4*)(yvf + (size_t)bq*784 + f4*4) = s;
}

// ---------------------------------------------------------------------------
// fold (stride-4, pad 3) + /mask -> y_cl[b][i][j][48]
// ---------------------------------------------------------------------------
template<int SC>
__global__ void k_fold_f32(const float* __restrict__ yvf, float* __restrict__ ycl)
{
  int idx = blockIdx.x*256 + threadIdx.x;
  if (idx >= 2*128*128) return;
  int j = idx & 127; int t = idx >> 7; int i = t & 127; int b = t >> 7;
  float a[16];
#pragma unroll
  for (int c=0;c<16;++c) a[c]=0.f;
  const float* yb = yvf + (size_t)b*1024*784;

  int drs[2], qis[2], cnti=0;
  int dcs[2], qjs[2], cntj=0;
#pragma unroll
  for (int dr=0; dr<7; ++dr) {
    int tr = i + 3 - dr;
    if (tr >= 0 && (tr & 3) == 0 && (tr >> 2) < 32) { drs[cnti]=dr; qis[cnti]=tr>>2; ++cnti; }
  }
#pragma unroll
  for (int dc=0; dc<7; ++dc) {
    int tc = j + 3 - dc;
    if (tc >= 0 && (tc & 3) == 0 && (tc >> 2) < 32) { dcs[cntj]=dc; qjs[cntj]=tc>>2; ++cntj; }
  }
  for (int u=0; u<cnti; ++u) {
    for (int v=0; v<cntj; ++v) {
      const float* src = yb + (size_t)(qis[u]*32 + qjs[v])*784 + (drs[u]*7 + dcs[v])*16;
      float4 v0 = *(const float4*)(src);
      float4 v1 = *(const float4*)(src+4);
      float4 v2 = *(const float4*)(src+8);
      float4 v3 = *(const float4*)(src+12);
      a[0]+=v0.x; a[1]+=v0.y; a[2]+=v0.z; a[3]+=v0.w;
      a[4]+=v1.x; a[5]+=v1.y; a[6]+=v1.z; a[7]+=v1.w;
      a[8]+=v2.x; a[9]+=v2.y; a[10]+=v2.z; a[11]+=v2.w;
      a[12]+=v3.x; a[13]+=v3.y; a[14]+=v3.z; a[15]+=v3.w;
    }
  }
  float inv = 1.0f / (float)(cnti*cntj);
  float* dst = ycl + (size_t)idx*48 + SC*16;
#pragma unroll
  for (int c=0;c<16;++c) dst[c] = a[c]*inv;
}

// ---------------------------------------------------------------------------
// out = conv1x1(y, w_out) + b_out + x
// ---------------------------------------------------------------------------
__global__ void k_final(const float* __restrict__ ycl, const float* __restrict__ wo,
                        const float* __restrict__ bo, const float* __restrict__ x,
                        float* __restrict__ out)
{
  __shared__ float wl[64*48];
  for (int t = threadIdx.x; t < 64*48; t += 256) wl[t] = wo[t];
  __syncthreads();
  int idx = blockIdx.x*256 + threadIdx.x;
  if (idx >= 2*128*128) return;
  int j = idx & 127; int t = idx >> 7; int i = t & 127; int b = t >> 7;
  float y[48];
  const float* ys = ycl + (size_t)idx*48;
#pragma unroll
  for (int c=0;c<48;++c) y[c] = ys[c];
  const float* xb = x + (size_t)b*64*16384 + i*128 + j;
  float* ob = out + (size_t)b*64*16384 + i*128 + j;
  for (int o=0;o<64;++o) {
    float s = bo[o];
#pragma unroll
    for (int c=0;c<48;++c) s += y[c]*wl[o*48+c];
    ob[(size_t)o*16384] = s + xb[(size_t)o*16384];
  }
}

// ---------------------------------------------------------------------------
extern "C" void kernel_launch(void* const* d_in, const int* in_sizes, int n_in,
                              void* d_out, int out_size, void* d_ws, size_t ws_size,
                              hipStream_t stream)
{
  const float* x  = (const float*)d_in[0];
  const float* wt = (const float*)d_in[1];
  const float* bt = (const float*)d_in[2];
  const float* wp0= (const float*)d_in[3];
  const float* bp0= (const float*)d_in[4];
  const float* wg0= (const float*)d_in[5];
  const float* bg0= (const float*)d_in[6];
  const float* wp1= (const float*)d_in[7];
  const float* bp1= (const float*)d_in[8];
  const float* wg1= (const float*)d_in[9];
  const float* bg1= (const float*)d_in[10];
  const float* wp2= (const float*)d_in[11];
  const float* bp2= (const float*)d_in[12];
  const float* wg2= (const float*)d_in[13];
  const float* bg2= (const float*)d_in[14];
  const float* wo = (const float*)d_in[15];
  const float* bo = (const float*)d_in[16];
  float* out = (float*)d_out;

  char* ws = (char*)d_ws;
  size_t off = 0;
  auto alloc = [&](size_t bytes)->char* { char* p = ws + off; off += (bytes + 255) & ~(size_t)255; return p; };
  unsigned short* th  = (unsigned short*)alloc(2ull*134*136*16*2);
  unsigned short* ph0 = (unsigned short*)alloc(2ull*134*136*16*2);
  unsigned short* ph1 = (unsigned short*)alloc(2ull*70*72*16*2);
  unsigned short* ph2 = (unsigned short*)alloc(2ull*38*40*16*2);
  float* gt0 = (float*)alloc(2ull*16*134*136*4);
  float* gt1 = (float*)alloc(2ull*16*70*72*4);
  float* gt2 = (float*)alloc(2ull*16*38*40*4);
  size_t zeroBytes = off;                      // th..gt2 contiguous prefix
  unsigned short* g80 = (unsigned short*)alloc(2ull*8*16*134*136*2);
  unsigned short* g81 = (unsigned short*)alloc(2ull*8*16*70*72*2);
  unsigned short* g82 = (unsigned short*)alloc(2ull*8*16*38*40*2);
  float* wT4 = (float*)alloc(1024ull*32*4);
  float* lP  = (float*)alloc(8ull*2*8*1024*4);
  float* lG  = (float*)alloc(2048*4);
  float* accP= (float*)alloc(8ull*2048*784*4);
  float* yvf = (float*)alloc(2048ull*784*4);
  float* ycl = (float*)alloc(2ull*128*128*48*4);
  (void)ws_size; (void)in_sizes; (void)n_in; (void)out_size;

  hipMemsetAsync(ws, 0, zeroBytes, stream);    // zero padded borders of th/ph/gt

  k_prep1<<<512,256,0,stream>>>(x, wt,bt, wp0,bp0, wg0,bg0, th, ph0, gt0);
  k_conv2<<<128,256,0,stream>>>(x, wp1,bp1, wg1,bg1, ph1, gt1);
  k_wt4<<<128,256,0,stream>>>(wp2, wg2, wT4);
  k_conv4<<<256,256,0,stream>>>(x, wT4, bp2, bg2, ph2, gt2);
  k_shift<134,136><<<(2*8*16*134*17+255)/256,256,0,stream>>>(gt0, g80);
  k_shift<70,72>  <<<(2*8*16*70*9 +255)/256,256,0,stream>>>(gt1, g81);
  k_shift<38,40>  <<<(2*8*16*38*5 +255)/256,256,0,stream>>>(gt2, g82);

  const int CB2 = (2048*196 + 255)/256;
  // ---- scale 0 (s=1): 16384 keys, 8 chunks of 2048 (4 iters), 512 blocks ----
  k_attn<128,7,134,136,2048,8><<<512,512,0,stream>>>(th, ph0, g80, accP, lP);
  k_comb1<<<8,256,0,stream>>>(lP, lG, 8);
  k_comb2<<<CB2,256,0,stream>>>(accP, lG, yvf, 8);
  k_fold_f32<0><<<128,256,0,stream>>>(yvf, ycl);
  // ---- scale 1 (s=2): 4096 keys, 8 chunks of 512 (2 iters), 512 blocks ----
  k_attn<64,6,70,72,512,8><<<512,512,0,stream>>>(th, ph1, g81, accP, lP);
  k_comb1<<<8,256,0,stream>>>(lP, lG, 8);
  k_comb2<<<CB2,256,0,stream>>>(accP, lG, yvf, 8);
  k_fold_f32<1><<<128,256,0,stream>>>(yvf, ycl);
  // ---- scale 2 (s=4): 1024 keys, 4 chunks of 256 (1 iter), 256 blocks ----
  k_attn<32,5,38,40,256,4><<<256,512,0,stream>>>(th, ph2, g82, accP, lP);
  k_comb1<<<8,256,0,stream>>>(lP, lG, 4);
  k_comb2<<<CB2,256,0,stream>>>(accP, lG, yvf, 4);
  k_fold_f32<2><<<128,256,0,stream>>>(yvf, ycl);

  k_final<<<128,256,0,stream>>>(ycl, wo, bo, x, out);
}

// Round 10
// 727.388 us; speedup vs baseline: 16.9725x; 1.0795x over previous
//
#include <hip/hip_runtime.h>
#include <stdint.h>

typedef __attribute__((ext_vector_type(8))) short bf16x8;
typedef __attribute__((ext_vector_type(4))) float f32x4;

#define DEV __device__ __forceinline__

DEV float bf2f(unsigned short u){ union{unsigned int i; float f;} v; v.i=((unsigned int)u)<<16; return v.f; }
DEV unsigned short f2bf(float f){ union{float f; unsigned int i;} v; v.f=f; unsigned int x=v.i;
  return (unsigned short)((x + 0x7fffu + ((x>>16)&1u)) >> 16); }

// ---------------------------------------------------------------------------
// Fused s=1 prep: theta = (W_t x + b_t)*10*log2(e)  [bf16 CL padded 134x136x16]
//                 phi0  = W_p x + b_p               [bf16 CL padded]
//                 g0    = W_g x + b_g               [f32 CF padded 16x134x136]
// ---------------------------------------------------------------------------
__global__ void k_prep1(const float* __restrict__ x,
                        const float* __restrict__ wt, const float* __restrict__ bt,
                        const float* __restrict__ wp, const float* __restrict__ bp,
                        const float* __restrict__ wg, const float* __restrict__ bg,
                        unsigned short* __restrict__ th, unsigned short* __restrict__ ph,
                        float* __restrict__ gt)
{
  __shared__ float red[3][64][48];
  int tid = threadIdx.x;
  int grp = tid >> 6, pixl = tid & 63;
  int pix = blockIdx.x*64 + pixl;          // [0, 32768)
  int b = pix >> 14, p = pix & 16383, i = p >> 7, j = p & 127;
  float a[48];
#pragma unroll
  for (int c=0;c<48;++c) a[c]=0.f;
  const float* xb = x + (size_t)b*64*16384 + p;
#pragma unroll
  for (int c4=0; c4<4; ++c4) {
    int cc = grp*16 + c4*4;
    float xv[4];
#pragma unroll
    for (int u=0;u<4;++u) xv[u] = xb[(size_t)(cc+u)*16384];
#pragma unroll
    for (int ic=0;ic<16;++ic) {
      float4 w0 = *(const float4*)(wt + ic*64 + cc);
      float4 w1 = *(const float4*)(wp + ic*64 + cc);
      float4 w2 = *(const float4*)(wg + ic*64 + cc);
      a[ic]    += xv[0]*w0.x + xv[1]*w0.y + xv[2]*w0.z + xv[3]*w0.w;
      a[16+ic] += xv[0]*w1.x + xv[1]*w1.y + xv[2]*w1.z + xv[3]*w1.w;
      a[32+ic] += xv[0]*w2.x + xv[1]*w2.y + xv[2]*w2.z + xv[3]*w2.w;
    }
  }
  if (grp) {
#pragma unroll
    for (int c=0;c<48;++c) red[grp-1][pixl][c] = a[c];
  }
  __syncthreads();
  if (grp == 0) {
#pragma unroll
    for (int c=0;c<48;++c) a[c] += red[0][pixl][c] + red[1][pixl][c] + red[2][pixl][c];
    const float TEMPC = 14.426950408889634f;
    unsigned short o[16];
#pragma unroll
    for (int ic=0;ic<16;++ic) o[ic] = f2bf((a[ic]+bt[ic])*TEMPC);
    uint4* d0 = (uint4*)(th + ((size_t)(b*134 + i+3)*136 + (j+3))*16);
    d0[0]=*(uint4*)&o[0]; d0[1]=*(uint4*)&o[8];
#pragma unroll
    for (int ic=0;ic<16;++ic) o[ic] = f2bf(a[16+ic]+bp[ic]);
    uint4* d1 = (uint4*)(ph + ((size_t)(b*134 + i+3)*136 + (j+3))*16);
    d1[0]=*(uint4*)&o[0]; d1[1]=*(uint4*)&o[8];
#pragma unroll
    for (int ic=0;ic<16;++ic)
      gt[(((size_t)b*16+ic)*134 + i+3)*136 + (j+3)] = a[32+ic]+bg[ic];
  }
}

// ---------------------------------------------------------------------------
// s=2 conv: phi1 (bf16 CL padded 70x72x16), g1 (f32 CF padded 16x70x72)
// ---------------------------------------------------------------------------
__global__ void k_conv2(const float* __restrict__ x,
                        const float* __restrict__ wp, const float* __restrict__ bp,
                        const float* __restrict__ wg, const float* __restrict__ bg,
                        unsigned short* __restrict__ phi, float* __restrict__ gt)
{
  __shared__ float red[3][64][32];
  int tid = threadIdx.x;
  int grp = tid >> 6, pixl = tid & 63;
  int pix = blockIdx.x*64 + pixl;          // [0, 8192)
  int b = pix >> 12, p = pix & 4095, i = p >> 6, j = p & 63;
  float a[32];
#pragma unroll
  for (int c=0;c<32;++c) a[c]=0.f;
  const float* xb = x + (size_t)b*64*16384 + (i*2)*128 + j*2;
#pragma unroll
  for (int c0=0; c0<16; ++c0) {
    int cc = grp*16 + c0;
    const float* xp = xb + (size_t)cc*16384;
    float xv[4];
    xv[0]=xp[0]; xv[1]=xp[1]; xv[2]=xp[128]; xv[3]=xp[129];
#pragma unroll
    for (int ic=0;ic<16;++ic) {
      float4 w0 = *(const float4*)(wp + (ic*64+cc)*4);
      float4 w1 = *(const float4*)(wg + (ic*64+cc)*4);
      a[ic]    += xv[0]*w0.x + xv[1]*w0.y + xv[2]*w0.z + xv[3]*w0.w;
      a[16+ic] += xv[0]*w1.x + xv[1]*w1.y + xv[2]*w1.z + xv[3]*w1.w;
    }
  }
  if (grp) {
#pragma unroll
    for (int c=0;c<32;++c) red[grp-1][pixl][c] = a[c];
  }
  __syncthreads();
  if (grp == 0) {
#pragma unroll
    for (int c=0;c<32;++c) a[c] += red[0][pixl][c] + red[1][pixl][c] + red[2][pixl][c];
    unsigned short o[16];
#pragma unroll
    for (int ic=0;ic<16;++ic) o[ic] = f2bf(a[ic]+bp[ic]);
    uint4* d1 = (uint4*)(phi + ((size_t)(b*70 + i+3)*72 + (j+3))*16);
    d1[0]=*(uint4*)&o[0]; d1[1]=*(uint4*)&o[8];
#pragma unroll
    for (int ic=0;ic<16;++ic)
      gt[(((size_t)b*16+ic)*70 + i+3)*72 + (j+3)] = a[16+ic]+bg[ic];
  }
}

// ---------------------------------------------------------------------------
// Transpose s=4 weights: wT[k][32], k = cc*16 + a*4 + bb; c<16 phi, else g
// ---------------------------------------------------------------------------
__global__ void k_wt4(const float* __restrict__ wp, const float* __restrict__ wg,
                      float* __restrict__ wT)
{
  int idx = blockIdx.x*256 + threadIdx.x;
  if (idx >= 1024*32) return;
  int k = idx >> 5, c = idx & 31;
  int cc = k >> 4, ksp = k & 15;
  float v = (c < 16) ? wp[(c*64+cc)*16 + ksp] : wg[((c-16)*64+cc)*16 + ksp];
  wT[idx] = v;
}

// ---------------------------------------------------------------------------
// s=4 conv: 8 pixels x 32 out-channels; x patches staged in LDS
// ---------------------------------------------------------------------------
__global__ void k_conv4(const float* __restrict__ x, const float* __restrict__ wT,
                        const float* __restrict__ bp, const float* __restrict__ bg,
                        unsigned short* __restrict__ phi, float* __restrict__ gt)
{
  __shared__ float xs[8][1028];
  int tid = threadIdx.x;
  int pix0 = blockIdx.x*8;                 // [0,2048) step 8
  for (int idx = tid; idx < 8*1024; idx += 256) {
    int pl = idx >> 10, e = idx & 1023;
    int pix = pix0 + pl; int b = pix >> 10, p = pix & 1023, i = p >> 5, j = p & 31;
    int cc = e >> 4, a_ = (e >> 2) & 3, bb = e & 3;
    xs[pl][e] = x[(((size_t)b*64+cc)*128 + i*4+a_)*128 + j*4+bb];
  }
  __syncthreads();
  int pp = tid >> 5, icp = tid & 31;
  int pix = pix0 + pp; int b = pix >> 10, p = pix & 1023, i = p >> 5, j = p & 31;
  float acc = 0.f;
#pragma unroll 8
  for (int k4=0; k4<256; ++k4) {
    float4 xv = *(const float4*)(&xs[pp][k4*4]);
    acc += xv.x*wT[(k4*4  )*32+icp] + xv.y*wT[(k4*4+1)*32+icp]
         + xv.z*wT[(k4*4+2)*32+icp] + xv.w*wT[(k4*4+3)*32+icp];
  }
  int ic = icp & 15;
  if (icp < 16)
    phi[(((size_t)(b*38 + i+3)*40) + (j+3))*16 + ic] = f2bf(acc + bp[ic]);
  else
    gt[(((size_t)b*16+ic)*38 + i+3)*40 + (j+3)] = acc + bg[ic];
}

// ---------------------------------------------------------------------------
// V tile buffer: g8b[b][sh][y][xb][c][32] bf16 (1KB tile per (sh,y,xb)).
// g8b tile element [c][xk] = g_pad[c][y][xb*32+xk+sh]; PV B-fragment load =
// one contiguous 1KB transaction (lane = c*64B + g*16B).
// ---------------------------------------------------------------------------
template<int HP, int WX, int HS>
__global__ void k_shiftB(const float* __restrict__ gt, unsigned short* __restrict__ g8b)
{
  const int XB = HS/32;
  int idx = blockIdx.x*256 + threadIdx.x;
  const int TOT = 2*8*HP*XB*16*4;
  if (idx >= TOT) return;
  int xkg = idx & 3;
  int c = (idx >> 2) & 15;
  int t = idx >> 6;
  int xb = t % XB; t /= XB;
  int y = t % HP; t /= HP;
  int sh = t & 7; int b = t >> 3;
  const float* src = gt + (((size_t)b*16+c)*HP + y)*WX + xb*32 + xkg*8 + sh;
  unsigned short o[8];
#pragma unroll
  for (int j=0;j<8;++j) o[j] = f2bf(src[j]);
  unsigned short* dst = g8b + ((((size_t)(b*8+sh)*HP + y)*XB + xb)*16 + c)*32 + xkg*8;
  *(uint4*)dst = *(uint4*)&o[0];
}

// ---------------------------------------------------------------------------
// Flash attention with FIXED softmax shift (P = exp2(min(sc-64, 120))).
// Q-tile 32, 8 waves, 256 keys/iter, 2 barriers/iter, XCD-swizzled grid.
// V from g8b tiles: one 1KB coalesced load per (et, ks2).
// ---------------------------------------------------------------------------
template<int HS, int LG, int HP, int WX, int CK, int NCH>
__global__ void __launch_bounds__(512, 2)
k_attn(const unsigned short* __restrict__ th, const unsigned short* __restrict__ phi,
       const unsigned short* __restrict__ g8b, float* __restrict__ accP,
       float* __restrict__ lP)
{
  __shared__ __align__(16) char smem[16384];   // P: 32 q x 256 k bf16

  int tid = threadIdx.x;
  int w = tid >> 6, lane = tid & 63, l15 = lane & 15, g = lane >> 4;
  int bid = blockIdx.x;
  int chunk, b, qt;
  if (NCH == 8) { chunk = bid & 7; b = (bid >> 3) & 1; qt = bid >> 4; }
  else          { chunk = bid & 3; b = (bid >> 2) & 1; qt = bid >> 3; }
  int q0 = qt * 32;

  f32x4 acc[2][7];
#pragma unroll
  for (int rt=0;rt<2;++rt)
#pragma unroll
    for (int et=0;et<7;++et) acc[rt][et] = f32x4{0.f,0.f,0.f,0.f};
  float lacc[2][4];
#pragma unroll
  for (int rt=0;rt<2;++rt)
#pragma unroll
    for (int r=0;r<4;++r) lacc[rt][r] = 0.f;

  const int XBv = HS/32;
  const char* thB  = (const char*)th  + (size_t)b*134*136*32;
  const char* phiB = (const char*)phi + (size_t)b*HP*WX*32;
  const char* g8B  = (const char*)g8b + (size_t)b*8*HP*XBv*1024;
  const int EPL = HP*XBv*1024;                 // bytes per shift-plane
  int laneVb = l15*64 + g*16;                  // within 1KB tile
  int xrP = (l15 & 7) << 4;                    // P-lds read swizzle
  int tb = ((4*qt+2)*136 + 4*l15 + 2)*32 + ((g&1)<<4);
  const bf16x8 ZV = {0,0,0,0,0,0,0,0};
  const int ITERS = CK/256;
  const float SHIFT = 64.0f, CLAMP = 120.0f;

#pragma unroll 1
  for (int it = 0; it < ITERS; ++it) {
    int k0 = chunk*CK + it*256;
    asm volatile("" : "+v"(tb));
    // ---------------- QK ----------------
    f32x4 sc[2][2];
#pragma unroll
    for (int rt=0;rt<2;++rt){ sc[rt][0]=f32x4{0.f,0.f,0.f,0.f}; sc[rt][1]=f32x4{0.f,0.f,0.f,0.f}; }
    int kr_w = (k0 + w*32) >> LG;
    int kc_w = (w*32) & (HS-1);
    int base0 = (kr_w*WX + kc_w + l15)*32 + ((g&1)<<4);
    int base1 = base0 + 512;
#pragma unroll
    for (int ks=0; ks<25; ++ks) {
      int p0 = 2*ks;
      int p1 = (2*ks+1 > 48) ? 48 : 2*ks+1;
      int KA0 = ((p0/7)*136 + (p0%7))*32;
      int KA1 = ((p1/7)*136 + (p1%7))*32;
      int KB0 = ((p0/7)*WX  + (p0%7))*32;
      int KB1 = ((p1/7)*WX  + (p1%7))*32;
      int selA = (g & 2) ? KA1 : KA0;
      int selB = (g & 2) ? KB1 : KB0;
      bf16x8 a0 = *(const bf16x8*)(thB + tb + selA);
      bf16x8 a1 = *(const bf16x8*)(thB + tb + selA + 2048);
      if (ks == 24) {
        bool z = (g & 2) != 0;
        a0 = z ? ZV : a0; a1 = z ? ZV : a1;
      }
      bf16x8 b0 = *(const bf16x8*)(phiB + base0 + selB);
      bf16x8 b1 = *(const bf16x8*)(phiB + base1 + selB);
      sc[0][0] = __builtin_amdgcn_mfma_f32_16x16x32_bf16(a0, b0, sc[0][0], 0,0,0);
      sc[0][1] = __builtin_amdgcn_mfma_f32_16x16x32_bf16(a0, b1, sc[0][1], 0,0,0);
      sc[1][0] = __builtin_amdgcn_mfma_f32_16x16x32_bf16(a1, b0, sc[1][0], 0,0,0);
      sc[1][1] = __builtin_amdgcn_mfma_f32_16x16x32_bf16(a1, b1, sc[1][1], 0,0,0);
    }
    // ---------------- P = exp2(min(S-64,120)), accumulate l, write P_lds ----------------
#pragma unroll
    for (int rt=0;rt<2;++rt) {
#pragma unroll
      for (int r=0;r<4;++r) {
        float pa = __builtin_amdgcn_exp2f(fminf(sc[rt][0][r] - SHIFT, CLAMP));
        float pb = __builtin_amdgcn_exp2f(fminf(sc[rt][1][r] - SHIFT, CLAMP));
        lacc[rt][r] += pa + pb;
        int q_ = rt*16 + g*4 + r;
        int offa = q_*512 + (w*32 + l15)*2;      offa ^= (q_&7)<<4;
        int offb = q_*512 + (w*32 + 16 + l15)*2; offb ^= (q_&7)<<4;
        *(unsigned short*)(smem + offa) = f2bf(pa);
        *(unsigned short*)(smem + offb) = f2bf(pb);
      }
    }
    __syncthreads();                               // P ready
    // ---------------- PV ----------------
    if (w < 7) {
#pragma unroll
      for (int ks2=0; ks2<8; ++ks2) {
        int kk = k0 + ks2*32;
        int krv = kk >> LG;
        int kcb = kk & (HS-1);
        bf16x8 pf[2];
#pragma unroll
        for (int rt=0;rt<2;++rt) {
          int off = (rt*16 + l15)*512 + ks2*64 + g*16;
          off ^= xrP;
          pf[rt] = *(const bf16x8*)(smem + off);
        }
        int vb = ((krv + w)*XBv + (kcb >> 5))*1024 + laneVb;
        bf16x8 vf[7];
#pragma unroll
        for (int et=0;et<7;++et)
          vf[et] = *(const bf16x8*)(g8B + vb + et*EPL);
#pragma unroll
        for (int rt=0;rt<2;++rt)
#pragma unroll
          for (int et=0;et<7;++et)
            acc[rt][et] = __builtin_amdgcn_mfma_f32_16x16x32_bf16(pf[rt], vf[et], acc[rt][et], 0,0,0);
      }
    }
    __syncthreads();                               // protect P for next iter
  }
  if (w < 7) {
    float* accB = accP + ((size_t)(chunk*2 + b)*1024)*784;
#pragma unroll
    for (int rt=0;rt<2;++rt)
#pragma unroll
      for (int et=0;et<7;++et)
#pragma unroll
        for (int r=0;r<4;++r)
          accB[(size_t)(q0 + rt*16 + g*4 + r)*784 + (w*7+et)*16 + l15] = acc[rt][et][r];
  }
  // per-wave l partials: reduce over the 16-lane group, write one slot per wave
#pragma unroll
  for (int st=1; st<16; st<<=1)
#pragma unroll
    for (int rt=0;rt<2;++rt)
#pragma unroll
      for (int r=0;r<4;++r) lacc[rt][r] += __shfl_xor(lacc[rt][r], st);
  if (l15 == 0) {
#pragma unroll
    for (int rt=0;rt<2;++rt)
#pragma unroll
      for (int r=0;r<4;++r)
        lP[((size_t)((chunk*2 + b)*8 + w) << 10) + q0 + rt*16 + g*4 + r] = lacc[rt][r];
  }
}

// ---------------------------------------------------------------------------
// lG[b*1024+q] = sum over chunks and waves of lP
// ---------------------------------------------------------------------------
__global__ void k_comb1(const float* __restrict__ lP, float* __restrict__ lG, int nch)
{
  int idx = blockIdx.x*256 + threadIdx.x;
  if (idx >= 2048) return;
  int b = idx >> 10, q = idx & 1023;
  float l = 0.f;
  for (int c=0;c<nch;++c)
#pragma unroll
    for (int w=0;w<8;++w)
      l += lP[((size_t)((c*2 + b)*8 + w) << 10) + q];
  lG[idx] = l;
}

// ---------------------------------------------------------------------------
// Sum partial accs over chunks (directly summable, shared shift), / lG
// ---------------------------------------------------------------------------
__global__ void k_comb2(const float* __restrict__ accP, const float* __restrict__ lG,
                        float* __restrict__ yvf, int nch)
{
  int idx = blockIdx.x*256 + threadIdx.x;
  if (idx >= 2048*196) return;
  int bq = idx / 196, f4 = idx % 196;
  float4 s = {0.f,0.f,0.f,0.f};
  for (int c=0;c<nch;++c) {
    float4 v = *(const float4*)(accP + ((size_t)(c*2048 + bq))*784 + f4*4);
    s.x += v.x; s.y += v.y; s.z += v.z; s.w += v.w;
  }
  float inv = 1.0f / lG[bq];
  s.x*=inv; s.y*=inv; s.z*=inv; s.w*=inv;
  *(float4*)(yvf + (size_t)bq*784 + f4*4) = s;
}

// ---------------------------------------------------------------------------
// fold (stride-4, pad 3) + /mask -> y_cl[b][i][j][48]
// ---------------------------------------------------------------------------
template<int SC>
__global__ void k_fold_f32(const float* __restrict__ yvf, float* __restrict__ ycl)
{
  int idx = blockIdx.x*256 + threadIdx.x;
  if (idx >= 2*128*128) return;
  int j = idx & 127; int t = idx >> 7; int i = t & 127; int b = t >> 7;
  float a[16];
#pragma unroll
  for (int c=0;c<16;++c) a[c]=0.f;
  const float* yb = yvf + (size_t)b*1024*784;

  int drs[2], qis[2], cnti=0;
  int dcs[2], qjs[2], cntj=0;
#pragma unroll
  for (int dr=0; dr<7; ++dr) {
    int tr = i + 3 - dr;
    if (tr >= 0 && (tr & 3) == 0 && (tr >> 2) < 32) { drs[cnti]=dr; qis[cnti]=tr>>2; ++cnti; }
  }
#pragma unroll
  for (int dc=0; dc<7; ++dc) {
    int tc = j + 3 - dc;
    if (tc >= 0 && (tc & 3) == 0 && (tc >> 2) < 32) { dcs[cntj]=dc; qjs[cntj]=tc>>2; ++cntj; }
  }
  for (int u=0; u<cnti; ++u) {
    for (int v=0; v<cntj; ++v) {
      const float* src = yb + (size_t)(qis[u]*32 + qjs[v])*784 + (drs[u]*7 + dcs[v])*16;
      float4 v0 = *(const float4*)(src);
      float4 v1 = *(const float4*)(src+4);
      float4 v2 = *(const float4*)(src+8);
      float4 v3 = *(const float4*)(src+12);
      a[0]+=v0.x; a[1]+=v0.y; a[2]+=v0.z; a[3]+=v0.w;
      a[4]+=v1.x; a[5]+=v1.y; a[6]+=v1.z; a[7]+=v1.w;
      a[8]+=v2.x; a[9]+=v2.y; a[10]+=v2.z; a[11]+=v2.w;
      a[12]+=v3.x; a[13]+=v3.y; a[14]+=v3.z; a[15]+=v3.w;
    }
  }
  float inv = 1.0f / (float)(cnti*cntj);
  float* dst = ycl + (size_t)idx*48 + SC*16;
#pragma unroll
  for (int c=0;c<16;++c) dst[c] = a[c]*inv;
}

// ---------------------------------------------------------------------------
// out = conv1x1(y, w_out) + b_out + x
// ---------------------------------------------------------------------------
__global__ void k_final(const float* __restrict__ ycl, const float* __restrict__ wo,
                        const float* __restrict__ bo, const float* __restrict__ x,
                        float* __restrict__ out)
{
  __shared__ float wl[64*48];
  for (int t = threadIdx.x; t < 64*48; t += 256) wl[t] = wo[t];
  __syncthreads();
  int idx = blockIdx.x*256 + threadIdx.x;
  if (idx >= 2*128*128) return;
  int j = idx & 127; int t = idx >> 7; int i = t & 127; int b = t >> 7;
  float y[48];
  const float* ys = ycl + (size_t)idx*48;
#pragma unroll
  for (int c=0;c<48;++c) y[c] = ys[c];
  const float* xb = x + (size_t)b*64*16384 + i*128 + j;
  float* ob = out + (size_t)b*64*16384 + i*128 + j;
  for (int o=0;o<64;++o) {
    float s = bo[o];
#pragma unroll
    for (int c=0;c<48;++c) s += y[c]*wl[o*48+c];
    ob[(size_t)o*16384] = s + xb[(size_t)o*16384];
  }
}

// ---------------------------------------------------------------------------
extern "C" void kernel_launch(void* const* d_in, const int* in_sizes, int n_in,
                              void* d_out, int out_size, void* d_ws, size_t ws_size,
                              hipStream_t stream)
{
  const float* x  = (const float*)d_in[0];
  const float* wt = (const float*)d_in[1];
  const float* bt = (const float*)d_in[2];
  const float* wp0= (const float*)d_in[3];
  const float* bp0= (const float*)d_in[4];
  const float* wg0= (const float*)d_in[5];
  const float* bg0= (const float*)d_in[6];
  const float* wp1= (const float*)d_in[7];
  const float* bp1= (const float*)d_in[8];
  const float* wg1= (const float*)d_in[9];
  const float* bg1= (const float*)d_in[10];
  const float* wp2= (const float*)d_in[11];
  const float* bp2= (const float*)d_in[12];
  const float* wg2= (const float*)d_in[13];
  const float* bg2= (const float*)d_in[14];
  const float* wo = (const float*)d_in[15];
  const float* bo = (const float*)d_in[16];
  float* out = (float*)d_out;

  char* ws = (char*)d_ws;
  size_t off = 0;
  auto alloc = [&](size_t bytes)->char* { char* p = ws + off; off += (bytes + 255) & ~(size_t)255; return p; };
  unsigned short* th  = (unsigned short*)alloc(2ull*134*136*16*2);
  unsigned short* ph0 = (unsigned short*)alloc(2ull*134*136*16*2);
  unsigned short* ph1 = (unsigned short*)alloc(2ull*70*72*16*2);
  unsigned short* ph2 = (unsigned short*)alloc(2ull*38*40*16*2);
  float* gt0 = (float*)alloc(2ull*16*134*136*4);
  float* gt1 = (float*)alloc(2ull*16*70*72*4);
  float* gt2 = (float*)alloc(2ull*16*38*40*4);
  size_t zeroBytes = off;                      // th..gt2 contiguous prefix
  unsigned short* g80 = (unsigned short*)alloc(2ull*8*134*4*512*2);
  unsigned short* g81 = (unsigned short*)alloc(2ull*8*70*2*512*2);
  unsigned short* g82 = (unsigned short*)alloc(2ull*8*38*1*512*2);
  float* wT4 = (float*)alloc(1024ull*32*4);
  float* lP  = (float*)alloc(8ull*2*8*1024*4);
  float* lG  = (float*)alloc(2048*4);
  float* accP= (float*)alloc(8ull*2048*784*4);
  float* yvf = (float*)alloc(2048ull*784*4);
  float* ycl = (float*)alloc(2ull*128*128*48*4);
  (void)ws_size; (void)in_sizes; (void)n_in; (void)out_size;

  hipMemsetAsync(ws, 0, zeroBytes, stream);    // zero padded borders of th/ph/gt

  k_prep1<<<512,256,0,stream>>>(x, wt,bt, wp0,bp0, wg0,bg0, th, ph0, gt0);
  k_conv2<<<128,256,0,stream>>>(x, wp1,bp1, wg1,bg1, ph1, gt1);
  k_wt4<<<128,256,0,stream>>>(wp2, wg2, wT4);
  k_conv4<<<256,256,0,stream>>>(x, wT4, bp2, bg2, ph2, gt2);
  k_shiftB<134,136,128><<<(2*8*134*4*16*4+255)/256,256,0,stream>>>(gt0, g80);
  k_shiftB<70,72,64>   <<<(2*8*70*2*16*4 +255)/256,256,0,stream>>>(gt1, g81);
  k_shiftB<38,40,32>   <<<(2*8*38*1*16*4 +255)/256,256,0,stream>>>(gt2, g82);

  const int CB2 = (2048*196 + 255)/256;
  // ---- scale 0 (s=1): 16384 keys, 8 chunks of 2048 (4 iters), 512 blocks ----
  k_attn<128,7,134,136,2048,8><<<512,512,0,stream>>>(th, ph0, g80, accP, lP);
  k_comb1<<<8,256,0,stream>>>(lP, lG, 8);
  k_comb2<<<CB2,256,0,stream>>>(accP, lG, yvf, 8);
  k_fold_f32<0><<<128,256,0,stream>>>(yvf, ycl);
  // ---- scale 1 (s=2): 4096 keys, 8 chunks of 512 (2 iters), 512 blocks ----
  k_attn<64,6,70,72,512,8><<<512,512,0,stream>>>(th, ph1, g81, accP, lP);
  k_comb1<<<8,256,0,stream>>>(lP, lG, 8);
  k_comb2<<<CB2,256,0,stream>>>(accP, lG, yvf, 8);
  k_fold_f32<1><<<128,256,0,stream>>>(yvf, ycl);
  // ---- scale 2 (s=4): 1024 keys, 4 chunks of 256 (1 iter), 256 blocks ----
  k_attn<32,5,38,40,256,4><<<256,512,0,stream>>>(th, ph2, g82, accP, lP);
  k_comb1<<<8,256,0,stream>>>(lP, lG, 4);
  k_comb2<<<CB2,256,0,stream>>>(accP, lG, yvf, 4);
  k_fold_f32<2><<<128,256,0,stream>>>(yvf, ycl);

  k_final<<<128,256,0,stream>>>(ycl, wo, bo, x, out);
}

// Round 12
// 573.555 us; speedup vs baseline: 21.5247x; 1.2682x over previous
//
#include <hip/hip_runtime.h>
#include <stdint.h>

typedef __attribute__((ext_vector_type(8))) short bf16x8;
typedef __attribute__((ext_vector_type(4))) float f32x4;
typedef __attribute__((ext_vector_type(4))) unsigned int u32x4;

#define DEV __device__ __forceinline__

DEV float bf2f(unsigned short u){ union{unsigned int i; float f;} v; v.i=((unsigned int)u)<<16; return v.f; }
DEV unsigned short f2bf(float f){ union{float f; unsigned int i;} v; v.f=f; unsigned int x=v.i;
  return (unsigned short)((x + 0x7fffu + ((x>>16)&1u)) >> 16); }

// ---------------------------------------------------------------------------
// Fused s=1 prep: theta = (W_t x + b_t)*10*log2(e)  [bf16 CL padded 134x136x16]
//                 phi0  = W_p x + b_p               [bf16 CL padded]
//                 g0    = W_g x + b_g               [f32 CF padded 16x134x136]
// ---------------------------------------------------------------------------
__global__ void k_prep1(const float* __restrict__ x,
                        const float* __restrict__ wt, const float* __restrict__ bt,
                        const float* __restrict__ wp, const float* __restrict__ bp,
                        const float* __restrict__ wg, const float* __restrict__ bg,
                        unsigned short* __restrict__ th, unsigned short* __restrict__ ph,
                        float* __restrict__ gt)
{
  __shared__ float red[3][64][48];
  int tid = threadIdx.x;
  int grp = tid >> 6, pixl = tid & 63;
  int pix = blockIdx.x*64 + pixl;          // [0, 32768)
  int b = pix >> 14, p = pix & 16383, i = p >> 7, j = p & 127;
  float a[48];
#pragma unroll
  for (int c=0;c<48;++c) a[c]=0.f;
  const float* xb = x + (size_t)b*64*16384 + p;
#pragma unroll
  for (int c4=0; c4<4; ++c4) {
    int cc = grp*16 + c4*4;
    float xv[4];
#pragma unroll
    for (int u=0;u<4;++u) xv[u] = xb[(size_t)(cc+u)*16384];
#pragma unroll
    for (int ic=0;ic<16;++ic) {
      float4 w0 = *(const float4*)(wt + ic*64 + cc);
      float4 w1 = *(const float4*)(wp + ic*64 + cc);
      float4 w2 = *(const float4*)(wg + ic*64 + cc);
      a[ic]    += xv[0]*w0.x + xv[1]*w0.y + xv[2]*w0.z + xv[3]*w0.w;
      a[16+ic] += xv[0]*w1.x + xv[1]*w1.y + xv[2]*w1.z + xv[3]*w1.w;
      a[32+ic] += xv[0]*w2.x + xv[1]*w2.y + xv[2]*w2.z + xv[3]*w2.w;
    }
  }
  if (grp) {
#pragma unroll
    for (int c=0;c<48;++c) red[grp-1][pixl][c] = a[c];
  }
  __syncthreads();
  if (grp == 0) {
#pragma unroll
    for (int c=0;c<48;++c) a[c] += red[0][pixl][c] + red[1][pixl][c] + red[2][pixl][c];
    const float TEMPC = 14.426950408889634f;
    unsigned short o[16];
#pragma unroll
    for (int ic=0;ic<16;++ic) o[ic] = f2bf((a[ic]+bt[ic])*TEMPC);
    uint4* d0 = (uint4*)(th + ((size_t)(b*134 + i+3)*136 + (j+3))*16);
    d0[0]=*(uint4*)&o[0]; d0[1]=*(uint4*)&o[8];
#pragma unroll
    for (int ic=0;ic<16;++ic) o[ic] = f2bf(a[16+ic]+bp[ic]);
    uint4* d1 = (uint4*)(ph + ((size_t)(b*134 + i+3)*136 + (j+3))*16);
    d1[0]=*(uint4*)&o[0]; d1[1]=*(uint4*)&o[8];
#pragma unroll
    for (int ic=0;ic<16;++ic)
      gt[(((size_t)b*16+ic)*134 + i+3)*136 + (j+3)] = a[32+ic]+bg[ic];
  }
}

// ---------------------------------------------------------------------------
// s=2 conv: phi1 (bf16 CL padded 70x72x16), g1 (f32 CF padded 16x70x72)
// ---------------------------------------------------------------------------
__global__ void k_conv2(const float* __restrict__ x,
                        const float* __restrict__ wp, const float* __restrict__ bp,
                        const float* __restrict__ wg, const float* __restrict__ bg,
                        unsigned short* __restrict__ phi, float* __restrict__ gt)
{
  __shared__ float red[3][64][32];
  int tid = threadIdx.x;
  int grp = tid >> 6, pixl = tid & 63;
  int pix = blockIdx.x*64 + pixl;          // [0, 8192)
  int b = pix >> 12, p = pix & 4095, i = p >> 6, j = p & 63;
  float a[32];
#pragma unroll
  for (int c=0;c<32;++c) a[c]=0.f;
  const float* xb = x + (size_t)b*64*16384 + (i*2)*128 + j*2;
#pragma unroll
  for (int c0=0; c0<16; ++c0) {
    int cc = grp*16 + c0;
    const float* xp = xb + (size_t)cc*16384;
    float xv[4];
    xv[0]=xp[0]; xv[1]=xp[1]; xv[2]=xp[128]; xv[3]=xp[129];
#pragma unroll
    for (int ic=0;ic<16;++ic) {
      float4 w0 = *(const float4*)(wp + (ic*64+cc)*4);
      float4 w1 = *(const float4*)(wg + (ic*64+cc)*4);
      a[ic]    += xv[0]*w0.x + xv[1]*w0.y + xv[2]*w0.z + xv[3]*w0.w;
      a[16+ic] += xv[0]*w1.x + xv[1]*w1.y + xv[2]*w1.z + xv[3]*w1.w;
    }
  }
  if (grp) {
#pragma unroll
    for (int c=0;c<32;++c) red[grp-1][pixl][c] = a[c];
  }
  __syncthreads();
  if (grp == 0) {
#pragma unroll
    for (int c=0;c<32;++c) a[c] += red[0][pixl][c] + red[1][pixl][c] + red[2][pixl][c];
    unsigned short o[16];
#pragma unroll
    for (int ic=0;ic<16;++ic) o[ic] = f2bf(a[ic]+bp[ic]);
    uint4* d1 = (uint4*)(phi + ((size_t)(b*70 + i+3)*72 + (j+3))*16);
    d1[0]=*(uint4*)&o[0]; d1[1]=*(uint4*)&o[8];
#pragma unroll
    for (int ic=0;ic<16;++ic)
      gt[(((size_t)b*16+ic)*70 + i+3)*72 + (j+3)] = a[16+ic]+bg[ic];
  }
}

// ---------------------------------------------------------------------------
// Transpose s=4 weights: wT[k][32], k = cc*16 + a*4 + bb; c<16 phi, else g
// ---------------------------------------------------------------------------
__global__ void k_wt4(const float* __restrict__ wp, const float* __restrict__ wg,
                      float* __restrict__ wT)
{
  int idx = blockIdx.x*256 + threadIdx.x;
  if (idx >= 1024*32) return;
  int k = idx >> 5, c = idx & 31;
  int cc = k >> 4, ksp = k & 15;
  float v = (c < 16) ? wp[(c*64+cc)*16 + ksp] : wg[((c-16)*64+cc)*16 + ksp];
  wT[idx] = v;
}

// ---------------------------------------------------------------------------
// s=4 conv: 8 pixels x 32 out-channels; x patches staged in LDS
// ---------------------------------------------------------------------------
__global__ void k_conv4(const float* __restrict__ x, const float* __restrict__ wT,
                        const float* __restrict__ bp, const float* __restrict__ bg,
                        unsigned short* __restrict__ phi, float* __restrict__ gt)
{
  __shared__ float xs[8][1028];
  int tid = threadIdx.x;
  int pix0 = blockIdx.x*8;                 // [0,2048) step 8
  for (int idx = tid; idx < 8*1024; idx += 256) {
    int pl = idx >> 10, e = idx & 1023;
    int pix = pix0 + pl; int b = pix >> 10, p = pix & 1023, i = p >> 5, j = p & 31;
    int cc = e >> 4, a_ = (e >> 2) & 3, bb = e & 3;
    xs[pl][e] = x[(((size_t)b*64+cc)*128 + i*4+a_)*128 + j*4+bb];
  }
  __syncthreads();
  int pp = tid >> 5, icp = tid & 31;
  int pix = pix0 + pp; int b = pix >> 10, p = pix & 1023, i = p >> 5, j = p & 31;
  float acc = 0.f;
#pragma unroll 8
  for (int k4=0; k4<256; ++k4) {
    float4 xv = *(const float4*)(&xs[pp][k4*4]);
    acc += xv.x*wT[(k4*4  )*32+icp] + xv.y*wT[(k4*4+1)*32+icp]
         + xv.z*wT[(k4*4+2)*32+icp] + xv.w*wT[(k4*4+3)*32+icp];
  }
  int ic = icp & 15;
  if (icp < 16)
    phi[(((size_t)(b*38 + i+3)*40) + (j+3))*16 + ic] = f2bf(acc + bp[ic]);
  else
    gt[(((size_t)b*16+ic)*38 + i+3)*40 + (j+3)] = acc + bg[ic];
}

// ---------------------------------------------------------------------------
// V tile buffer: g8b[b][sh][y][xb][c][32] bf16 (1KB tile per (sh,y,xb)).
// ---------------------------------------------------------------------------
template<int HP, int WX, int HS>
__global__ void k_shiftB(const float* __restrict__ gt, unsigned short* __restrict__ g8b)
{
  const int XB = HS/32;
  int idx = blockIdx.x*256 + threadIdx.x;
  const int TOT = 2*8*HP*XB*16*4;
  if (idx >= TOT) return;
  int xkg = idx & 3;
  int c = (idx >> 2) & 15;
  int t = idx >> 6;
  int xb = t % XB; t /= XB;
  int y = t % HP; t /= HP;
  int sh = t & 7; int b = t >> 3;
  const float* src = gt + (((size_t)b*16+c)*HP + y)*WX + xb*32 + xkg*8 + sh;
  unsigned short o[8];
#pragma unroll
  for (int j=0;j<8;++j) o[j] = f2bf(src[j]);
  unsigned short* dst = g8b + ((((size_t)(b*8+sh)*HP + y)*XB + xb)*16 + c)*32 + xkg*8;
  *(uint4*)dst = *(uint4*)&o[0];
}

// ---------------------------------------------------------------------------
// Flash attention, fixed shift P = exp2(min(sc-64,120)). Q-tile 32, 8 waves,
// 256 keys/iter. theta staged ONCE into swizzled LDS (shared by all waves,
// all iters -> QK A-fragments are LDS reads). V loads nontemporal (keep phi
// window L1-resident). accP stores nontemporal.
// ---------------------------------------------------------------------------
template<int HS, int LG, int HP, int WX, int CK, int NCH>
__global__ void __launch_bounds__(512, 2)
k_attn(const unsigned short* __restrict__ th, const unsigned short* __restrict__ phi,
       const unsigned short* __restrict__ g8b, float* __restrict__ accP,
       float* __restrict__ lP)
{
  // LDS: theta window 7*136*32 = 30464 B, then P 32q x 256k bf16 = 16384 B
  __shared__ __align__(16) char smem[30464 + 16384];
  const int PO = 30464;

  int tid = threadIdx.x;
  int w = tid >> 6, lane = tid & 63, l15 = lane & 15, g = lane >> 4;
  int bid = blockIdx.x;
  int chunk, b, qt;
  if (NCH == 8) { chunk = bid & 7; b = (bid >> 3) & 1; qt = bid >> 4; }
  else          { chunk = bid & 3; b = (bid >> 2) & 1; qt = bid >> 3; }
  int q0 = qt * 32;

  const char* thB  = (const char*)th  + (size_t)b*134*136*32;
  const char* phiB = (const char*)phi + (size_t)b*HP*WX*32;

  // ---- stage theta window (rows 4qt+2 .. 4qt+8) into swizzled LDS ----
  for (int u = tid; u < 7*136*2; u += 512) {
    int half = u & 1; int cu = (u >> 1) % 136; int r = (u >> 1) / 136;
    uint4 v = *(const uint4*)(thB + (((4*qt+2+r)*136 + cu)*32 + half*16));
    int la = (((r*136 + cu)*32) + half*16) ^ (((cu >> 2) & 7) << 4);
    *(uint4*)(smem + la) = v;
  }
  __syncthreads();

  f32x4 acc[2][7];
#pragma unroll
  for (int rt=0;rt<2;++rt)
#pragma unroll
    for (int et=0;et<7;++et) acc[rt][et] = f32x4{0.f,0.f,0.f,0.f};
  float lacc[2][4];
#pragma unroll
  for (int rt=0;rt<2;++rt)
#pragma unroll
    for (int r=0;r<4;++r) lacc[rt][r] = 0.f;

  const int XBv = HS/32;
  const char* g8B  = (const char*)g8b + (size_t)b*8*HP*XBv*1024;
  const int EPL = HP*XBv*1024;                 // bytes per shift-plane
  int laneVb = l15*64 + g*16;                  // within 1KB tile
  int xrP = (l15 & 7) << 4;                    // P-lds read swizzle
  int colb = 4*l15 + 2;                        // theta col base (a0); a1 = +64
  int hb = (g & 1) << 4;
  const bf16x8 ZV = {0,0,0,0,0,0,0,0};
  const int ITERS = CK/256;
  const float SHIFT = 64.0f, CLAMP = 120.0f;

#pragma unroll 1
  for (int it = 0; it < ITERS; ++it) {
    int k0 = chunk*CK + it*256;
    // ---------------- QK ----------------
    f32x4 sc[2][2];
#pragma unroll
    for (int rt=0;rt<2;++rt){ sc[rt][0]=f32x4{0.f,0.f,0.f,0.f}; sc[rt][1]=f32x4{0.f,0.f,0.f,0.f}; }
    int kr_w = (k0 + w*32) >> LG;
    int kc_w = (w*32) & (HS-1);
    int base0 = (kr_w*WX + kc_w + l15)*32 + ((g&1)<<4);
    int base1 = base0 + 512;
#pragma unroll
    for (int ks=0; ks<25; ++ks) {
      int p0 = 2*ks;
      int p1 = (2*ks+1 > 48) ? 48 : 2*ks+1;
      int dr0 = p0/7, dc0 = p0%7;
      int dr1 = p1/7, dc1 = p1%7;
      // theta LDS addresses (swizzled)
      int c0 = colb + dc0, c1 = colb + dc1;
      int la0 = ((dr0*136 + c0)*32 + hb) ^ (((c0 >> 2) & 7) << 4);
      int la1 = ((dr1*136 + c1)*32 + hb) ^ (((c1 >> 2) & 7) << 4);
      int laA = (g & 2) ? la1 : la0;
      int KB0 = ((p0/7)*WX  + (p0%7))*32;
      int KB1 = ((p1/7)*WX  + (p1%7))*32;
      int selB = (g & 2) ? KB1 : KB0;
      bf16x8 a0 = *(const bf16x8*)(smem + laA);
      bf16x8 a1 = *(const bf16x8*)(smem + laA + 2048);   // +64 cols, same swizzle
      if (ks == 24) {
        bool z = (g & 2) != 0;
        a0 = z ? ZV : a0; a1 = z ? ZV : a1;
      }
      bf16x8 b0 = *(const bf16x8*)(phiB + base0 + selB);
      bf16x8 b1 = *(const bf16x8*)(phiB + base1 + selB);
      sc[0][0] = __builtin_amdgcn_mfma_f32_16x16x32_bf16(a0, b0, sc[0][0], 0,0,0);
      sc[0][1] = __builtin_amdgcn_mfma_f32_16x16x32_bf16(a0, b1, sc[0][1], 0,0,0);
      sc[1][0] = __builtin_amdgcn_mfma_f32_16x16x32_bf16(a1, b0, sc[1][0], 0,0,0);
      sc[1][1] = __builtin_amdgcn_mfma_f32_16x16x32_bf16(a1, b1, sc[1][1], 0,0,0);
    }
    // ---------------- P = exp2(min(S-64,120)), accumulate l, write P_lds ----------------
#pragma unroll
    for (int rt=0;rt<2;++rt) {
#pragma unroll
      for (int r=0;r<4;++r) {
        float pa = __builtin_amdgcn_exp2f(fminf(sc[rt][0][r] - SHIFT, CLAMP));
        float pb = __builtin_amdgcn_exp2f(fminf(sc[rt][1][r] - SHIFT, CLAMP));
        lacc[rt][r] += pa + pb;
        int q_ = rt*16 + g*4 + r;
        int offa = q_*512 + (w*32 + l15)*2;      offa ^= (q_&7)<<4;
        int offb = q_*512 + (w*32 + 16 + l15)*2; offb ^= (q_&7)<<4;
        *(unsigned short*)(smem + PO + offa) = f2bf(pa);
        *(unsigned short*)(smem + PO + offb) = f2bf(pb);
      }
    }
    __syncthreads();                               // P ready
    // ---------------- PV ----------------
    if (w < 7) {
#pragma unroll
      for (int ks2=0; ks2<8; ++ks2) {
        int kk = k0 + ks2*32;
        int krv = kk >> LG;
        int kcb = kk & (HS-1);
        bf16x8 pf[2];
#pragma unroll
        for (int rt=0;rt<2;++rt) {
          int off = (rt*16 + l15)*512 + ks2*64 + g*16;
          off ^= xrP;
          pf[rt] = *(const bf16x8*)(smem + PO + off);
        }
        int vb = ((krv + w)*XBv + (kcb >> 5))*1024 + laneVb;
        bf16x8 vf[7];
#pragma unroll
        for (int et=0;et<7;++et) {
          u32x4 t0 = __builtin_nontemporal_load((const u32x4*)(g8B + vb + et*EPL));
          vf[et] = *(bf16x8*)&t0;
        }
#pragma unroll
        for (int rt=0;rt<2;++rt)
#pragma unroll
          for (int et=0;et<7;++et)
            acc[rt][et] = __builtin_amdgcn_mfma_f32_16x16x32_bf16(pf[rt], vf[et], acc[rt][et], 0,0,0);
      }
    }
    __syncthreads();                               // protect P for next iter
  }
  if (w < 7) {
    float* accB = accP + ((size_t)(chunk*2 + b)*1024)*784;
#pragma unroll
    for (int rt=0;rt<2;++rt)
#pragma unroll
      for (int et=0;et<7;++et)
#pragma unroll
        for (int r=0;r<4;++r)
          __builtin_nontemporal_store(acc[rt][et][r],
            &accB[(size_t)(q0 + rt*16 + g*4 + r)*784 + (w*7+et)*16 + l15]);
  }
  // per-wave l partials: reduce over the 16-lane group, write one slot per wave
#pragma unroll
  for (int st=1; st<16; st<<=1)
#pragma unroll
    for (int rt=0;rt<2;++rt)
#pragma unroll
      for (int r=0;r<4;++r) lacc[rt][r] += __shfl_xor(lacc[rt][r], st);
  if (l15 == 0) {
#pragma unroll
    for (int rt=0;rt<2;++rt)
#pragma unroll
      for (int r=0;r<4;++r)
        lP[((size_t)((chunk*2 + b)*8 + w) << 10) + q0 + rt*16 + g*4 + r] = lacc[rt][r];
  }
}

// ---------------------------------------------------------------------------
// lG[b*1024+q] = sum over chunks and waves of lP
// ---------------------------------------------------------------------------
__global__ void k_comb1(const float* __restrict__ lP, float* __restrict__ lG, int nch)
{
  int idx = blockIdx.x*256 + threadIdx.x;
  if (idx >= 2048) return;
  int b = idx >> 10, q = idx & 1023;
  float l = 0.f;
  for (int c=0;c<nch;++c)
#pragma unroll
    for (int w=0;w<8;++w)
      l += lP[((size_t)((c*2 + b)*8 + w) << 10) + q];
  lG[idx] = l;
}

// ---------------------------------------------------------------------------
// Sum partial accs over chunks (directly summable, shared shift), / lG
// ---------------------------------------------------------------------------
__global__ void k_comb2(const float* __restrict__ accP, const float* __restrict__ lG,
                        float* __restrict__ yvf, int nch)
{
  int idx = blockIdx.x*256 + threadIdx.x;
  if (idx >= 2048*196) return;
  int bq = idx / 196, f4 = idx % 196;
  float4 s = {0.f,0.f,0.f,0.f};
  for (int c=0;c<nch;++c) {
    float4 v = *(const float4*)(accP + ((size_t)(c*2048 + bq))*784 + f4*4);
    s.x += v.x; s.y += v.y; s.z += v.z; s.w += v.w;
  }
  float inv = 1.0f / lG[bq];
  s.x*=inv; s.y*=inv; s.z*=inv; s.w*=inv;
  *(float4*)(yvf + (size_t)bq*784 + f4*4) = s;
}

// ---------------------------------------------------------------------------
// fold (stride-4, pad 3) + /mask -> y_cl[b][i][j][48]
// ---------------------------------------------------------------------------
template<int SC>
__global__ void k_fold_f32(const float* __restrict__ yvf, float* __restrict__ ycl)
{
  int idx = blockIdx.x*256 + threadIdx.x;
  if (idx >= 2*128*128) return;
  int j = idx & 127; int t = idx >> 7; int i = t & 127; int b = t >> 7;
  float a[16];
#pragma unroll
  for (int c=0;c<16;++c) a[c]=0.f;
  const float* yb = yvf + (size_t)b*1024*784;

  int drs[2], qis[2], cnti=0;
  int dcs[2], qjs[2], cntj=0;
#pragma unroll
  for (int dr=0; dr<7; ++dr) {
    int tr = i + 3 - dr;
    if (tr >= 0 && (tr & 3) == 0 && (tr >> 2) < 32) { drs[cnti]=dr; qis[cnti]=tr>>2; ++cnti; }
  }
#pragma unroll
  for (int dc=0; dc<7; ++dc) {
    int tc = j + 3 - dc;
    if (tc >= 0 && (tc & 3) == 0 && (tc >> 2) < 32) { dcs[cntj]=dc; qjs[cntj]=tc>>2; ++cntj; }
  }
  for (int u=0; u<cnti; ++u) {
    for (int v=0; v<cntj; ++v) {
      const float* src = yb + (size_t)(qis[u]*32 + qjs[v])*784 + (drs[u]*7 + dcs[v])*16;
      float4 v0 = *(const float4*)(src);
      float4 v1 = *(const float4*)(src+4);
      float4 v2 = *(const float4*)(src+8);
      float4 v3 = *(const float4*)(src+12);
      a[0]+=v0.x; a[1]+=v0.y; a[2]+=v0.z; a[3]+=v0.w;
      a[4]+=v1.x; a[5]+=v1.y; a[6]+=v1.z; a[7]+=v1.w;
      a[8]+=v2.x; a[9]+=v2.y; a[10]+=v2.z; a[11]+=v2.w;
      a[12]+=v3.x; a[13]+=v3.y; a[14]+=v3.z; a[15]+=v3.w;
    }
  }
  float inv = 1.0f / (float)(cnti*cntj);
  float* dst = ycl + (size_t)idx*48 + SC*16;
#pragma unroll
  for (int c=0;c<16;++c) dst[c] = a[c]*inv;
}

// ---------------------------------------------------------------------------
// out = conv1x1(y, w_out) + b_out + x
// ---------------------------------------------------------------------------
__global__ void k_final(const float* __restrict__ ycl, const float* __restrict__ wo,
                        const float* __restrict__ bo, const float* __restrict__ x,
                        float* __restrict__ out)
{
  __shared__ float wl[64*48];
  for (int t = threadIdx.x; t < 64*48; t += 256) wl[t] = wo[t];
  __syncthreads();
  int idx = blockIdx.x*256 + threadIdx.x;
  if (idx >= 2*128*128) return;
  int j = idx & 127; int t = idx >> 7; int i = t & 127; int b = t >> 7;
  float y[48];
  const float* ys = ycl + (size_t)idx*48;
#pragma unroll
  for (int c=0;c<48;++c) y[c] = ys[c];
  const float* xb = x + (size_t)b*64*16384 + i*128 + j;
  float* ob = out + (size_t)b*64*16384 + i*128 + j;
  for (int o=0;o<64;++o) {
    float s = bo[o];
#pragma unroll
    for (int c=0;c<48;++c) s += y[c]*wl[o*48+c];
    ob[(size_t)o*16384] = s + xb[(size_t)o*16384];
  }
}

// ---------------------------------------------------------------------------
extern "C" void kernel_launch(void* const* d_in, const int* in_sizes, int n_in,
                              void* d_out, int out_size, void* d_ws, size_t ws_size,
                              hipStream_t stream)
{
  const float* x  = (const float*)d_in[0];
  const float* wt = (const float*)d_in[1];
  const float* bt = (const float*)d_in[2];
  const float* wp0= (const float*)d_in[3];
  const float* bp0= (const float*)d_in[4];
  const float* wg0= (const float*)d_in[5];
  const float* bg0= (const float*)d_in[6];
  const float* wp1= (const float*)d_in[7];
  const float* bp1= (const float*)d_in[8];
  const float* wg1= (const float*)d_in[9];
  const float* bg1= (const float*)d_in[10];
  const float* wp2= (const float*)d_in[11];
  const float* bp2= (const float*)d_in[12];
  const float* wg2= (const float*)d_in[13];
  const float* bg2= (const float*)d_in[14];
  const float* wo = (const float*)d_in[15];
  const float* bo = (const float*)d_in[16];
  float* out = (float*)d_out;

  char* ws = (char*)d_ws;
  size_t off = 0;
  auto alloc = [&](size_t bytes)->char* { char* p = ws + off; off += (bytes + 255) & ~(size_t)255; return p; };
  unsigned short* th  = (unsigned short*)alloc(2ull*134*136*16*2);
  unsigned short* ph0 = (unsigned short*)alloc(2ull*134*136*16*2);
  unsigned short* ph1 = (unsigned short*)alloc(2ull*70*72*16*2);
  unsigned short* ph2 = (unsigned short*)alloc(2ull*38*40*16*2);
  float* gt0 = (float*)alloc(2ull*16*134*136*4);
  float* gt1 = (float*)alloc(2ull*16*70*72*4);
  float* gt2 = (float*)alloc(2ull*16*38*40*4);
  size_t zeroBytes = off;                      // th..gt2 contiguous prefix
  unsigned short* g80 = (unsigned short*)alloc(2ull*8*134*4*512*2);
  unsigned short* g81 = (unsigned short*)alloc(2ull*8*70*2*512*2);
  unsigned short* g82 = (unsigned short*)alloc(2ull*8*38*1*512*2);
  float* wT4 = (float*)alloc(1024ull*32*4);
  float* lP  = (float*)alloc(8ull*2*8*1024*4);
  float* lG  = (float*)alloc(2048*4);
  float* accP= (float*)alloc(8ull*2048*784*4);
  float* yvf = (float*)alloc(2048ull*784*4);
  float* ycl = (float*)alloc(2ull*128*128*48*4);
  (void)ws_size; (void)in_sizes; (void)n_in; (void)out_size;

  (void)hipMemsetAsync(ws, 0, zeroBytes, stream);  // zero padded borders of th/ph/gt

  k_prep1<<<512,256,0,stream>>>(x, wt,bt, wp0,bp0, wg0,bg0, th, ph0, gt0);
  k_conv2<<<128,256,0,stream>>>(x, wp1,bp1, wg1,bg1, ph1, gt1);
  k_wt4<<<128,256,0,stream>>>(wp2, wg2, wT4);
  k_conv4<<<256,256,0,stream>>>(x, wT4, bp2, bg2, ph2, gt2);
  k_shiftB<134,136,128><<<(2*8*134*4*16*4+255)/256,256,0,stream>>>(gt0, g80);
  k_shiftB<70,72,64>   <<<(2*8*70*2*16*4 +255)/256,256,0,stream>>>(gt1, g81);
  k_shiftB<38,40,32>   <<<(2*8*38*1*16*4 +255)/256,256,0,stream>>>(gt2, g82);

  const int CB2 = (2048*196 + 255)/256;
  // ---- scale 0 (s=1): 16384 keys, 8 chunks of 2048 (4 iters), 512 blocks ----
  k_attn<128,7,134,136,2048,8><<<512,512,0,stream>>>(th, ph0, g80, accP, lP);
  k_comb1<<<8,256,0,stream>>>(lP, lG, 8);
  k_comb2<<<CB2,256,0,stream>>>(accP, lG, yvf, 8);
  k_fold_f32<0><<<128,256,0,stream>>>(yvf, ycl);
  // ---- scale 1 (s=2): 4096 keys, 8 chunks of 512 (2 iters), 512 blocks ----
  k_attn<64,6,70,72,512,8><<<512,512,0,stream>>>(th, ph1, g81, accP, lP);
  k_comb1<<<8,256,0,stream>>>(lP, lG, 8);
  k_comb2<<<CB2,256,0,stream>>>(accP, lG, yvf, 8);
  k_fold_f32<1><<<128,256,0,stream>>>(yvf, ycl);
  // ---- scale 2 (s=4): 1024 keys, 4 chunks of 256 (1 iter), 256 blocks ----
  k_attn<32,5,38,40,256,4><<<256,512,0,stream>>>(th, ph2, g82, accP, lP);
  k_comb1<<<8,256,0,stream>>>(lP, lG, 4);
  k_comb2<<<CB2,256,0,stream>>>(accP, lG, yvf, 4);
  k_fold_f32<2><<<128,256,0,stream>>>(yvf, ycl);

  k_final<<<128,256,0,stream>>>(ycl, wo, bo, x, out);
}